// Round 6
// baseline (483.909 us; speedup 1.0000x reference)
//
#include <hip/hip_runtime.h>

#define N_NODES 50000
#define N_EDGES 800000
#define D 128
#define N_LABELS 4096
#define HB 256           // histogram blocks
#define HWORDS 12500     // 50000/4 packed u8 counters per block (50 KB LDS)
#define NSLICE 8         // 8 column slices of 16 floats (64 B)
#define NB_NODE 12500    // node-blocks per pass (4 nodes/block)

// ---------------------------------------------------------------------------
// src out-degree histogram: per-block LDS (packed 4 x u8 per u32), no global atomics
// ---------------------------------------------------------------------------

__global__ __launch_bounds__(256) void src_hist_kernel(const int* __restrict__ src,
                                                       unsigned int* __restrict__ Hsrc) {
    __shared__ unsigned int hist[HWORDS];
    int t = threadIdx.x;
    for (int i = t; i < HWORDS; i += 256) hist[i] = 0;
    __syncthreads();
    int base = blockIdx.x * (N_EDGES / HB);
    int end = base + (N_EDGES / HB);
    for (int e = base + t; e < end; e += 256) {
        int n = src[e];
        atomicAdd(&hist[n >> 2], 1u << ((n & 3) * 8));
    }
    __syncthreads();
    unsigned int* outp = Hsrc + (size_t)blockIdx.x * HWORDS;
    for (int i = t; i < HWORDS; i += 256) outp[i] = hist[i];
}

// ---------------------------------------------------------------------------
// dst counts + edge position capture (the only remaining global atomics)
// ---------------------------------------------------------------------------

__global__ void count_kernel(const int* __restrict__ dst, int* __restrict__ cnt_in,
                             int* __restrict__ epos) {
    int e = blockIdx.x * 256 + threadIdx.x;
    if (e >= N_EDGES) return;
    epos[e] = atomicAdd(&cnt_in[dst[e]], 1);
}

// ---------------------------------------------------------------------------
// merge src partials + compute dinv vectors
// ---------------------------------------------------------------------------

__global__ void dinv_kernel(const unsigned int* __restrict__ Hsrc,
                            const int* __restrict__ cnt_in,
                            float* __restrict__ dinv_out, float* __restrict__ dinv_in,
                            float* __restrict__ dinv_io) {
    int n = blockIdx.x * 256 + threadIdx.x;
    if (n >= N_NODES) return;
    int w = n >> 2, sh = (n & 3) * 8;
    unsigned int s = 0;
#pragma unroll 8
    for (int b = 0; b < HB; ++b) s += (Hsrc[(size_t)b * HWORDS + w] >> sh) & 0xFFu;
    int co = (int)s;
    int ci = cnt_in[n];
    float do_ = (co > 0) ? 1.0f / sqrtf((float)co) : 0.0f;
    float di_ = (ci > 0) ? 1.0f / sqrtf((float)ci) : 0.0f;
    dinv_out[n] = do_;
    dinv_in[n] = di_;
    dinv_io[n] = do_ * di_;
}

// ---------------------------------------------------------------------------
// generic block scan (inclusive into out[i+1]; out[0]=0 via scan_add)
// ---------------------------------------------------------------------------

__global__ void scan_blocks_kernel(const int* __restrict__ cnt, int* __restrict__ outv,
                                   int* __restrict__ blocksums) {
    __shared__ int s[256];
    int t = threadIdx.x;
    int i = blockIdx.x * 256 + t;
    int v = (i < N_NODES) ? cnt[i] : 0;
    s[t] = v;
    __syncthreads();
    for (int offs = 1; offs < 256; offs <<= 1) {
        int add = (t >= offs) ? s[t - offs] : 0;
        __syncthreads();
        s[t] += add;
        __syncthreads();
    }
    if (i < N_NODES) outv[i + 1] = s[t];
    if (t == 255) blocksums[blockIdx.x] = s[255];
}

__global__ void scan_top_kernel(const int* __restrict__ blocksums, int* __restrict__ blockoffs,
                                int nblocks) {
    __shared__ int s[256];
    int t = threadIdx.x;
    int v = (t < nblocks) ? blocksums[t] : 0;
    s[t] = v;
    __syncthreads();
    for (int offs = 1; offs < 256; offs <<= 1) {
        int add = (t >= offs) ? s[t - offs] : 0;
        __syncthreads();
        s[t] += add;
        __syncthreads();
    }
    blockoffs[t] = s[t] - v;  // exclusive
}

__global__ void scan_add_kernel(int* __restrict__ outv, const int* __restrict__ blockoffs) {
    int i = blockIdx.x * 256 + threadIdx.x;
    if (i < N_NODES) outv[i + 1] += blockoffs[blockIdx.x];
    if (i == 0) outv[0] = 0;
}

__global__ void fill_csr_kernel(const int* __restrict__ src, const int* __restrict__ dst,
                                const int* __restrict__ row_off, const int* __restrict__ epos,
                                int* __restrict__ csr_src) {
    int e = blockIdx.x * 256 + threadIdx.x;
    if (e >= N_EDGES) return;
    int d = dst[e];
    csr_src[row_off[d] + epos[e]] = src[e];
}

// ---------------------------------------------------------------------------
// bias-propagation vectors, wave-parallel gather:
//   o1[n] = s1[n] * sum_{s in Nin(n)} g[s] ; o2[n] = s2[n] * same (optional)
// ---------------------------------------------------------------------------

__global__ __launch_bounds__(256) void uvec_kernel(
        const int* __restrict__ csr_src, const int* __restrict__ row_off,
        const float* __restrict__ gvec, const float* __restrict__ s1,
        const float* __restrict__ s2, float* __restrict__ o1, float* __restrict__ o2) {
    int wave = threadIdx.x >> 6;
    int lane = threadIdx.x & 63;
    int n = blockIdx.x * 4 + wave;
    if (n >= N_NODES) return;
    int start = row_off[n], end = row_off[n + 1];
    float a = 0.f;
    for (int j = start + lane; j < end; j += 64) a += gvec[csr_src[j]];
#pragma unroll
    for (int m = 32; m; m >>= 1) a += __shfl_xor(a, m, 64);
    if (lane == 0) {
        o1[n] = s1[n] * a;
        if (o2) o2[n] = s2[n] * a;
    }
}

__global__ void gatherl_kernel(const int* __restrict__ labels, const float* __restrict__ u1,
                               const float* __restrict__ u2, float* __restrict__ u1l,
                               float* __restrict__ u2l) {
    int i = blockIdx.x * 256 + threadIdx.x;
    if (i >= N_LABELS) return;
    int n = labels[i];
    u1l[i] = u1[n];
    u2l[i] = u2[n];
}

// ---------------------------------------------------------------------------
// active set for agg2: nodes appearing as src of any label-row edge
// ---------------------------------------------------------------------------

__global__ void flag_kernel(const int* __restrict__ labels, const int* __restrict__ row_off,
                            const int* __restrict__ csr_src, int* __restrict__ flag) {
    int i = blockIdx.x * 256 + threadIdx.x;
    if (i >= N_LABELS) return;
    int n = labels[i];
    int a = row_off[n], bnd = row_off[n + 1];
    for (int j = a; j < bnd; ++j) flag[csr_src[j]] = 1;
}

__global__ void compact_kernel(const int* __restrict__ flag, const int* __restrict__ fpos,
                               int* __restrict__ active) {
    int n = blockIdx.x * 256 + threadIdx.x;
    if (n >= N_NODES) return;
    if (flag[n]) active[fpos[n]] = n;
}

// ---------------------------------------------------------------------------
// prescale + repack slice-major: p0s[p][n][0:16] = feat[n][16p:16p+16] * dinv_out[n]
// ---------------------------------------------------------------------------

__global__ void prescale_slice_kernel(const float4* __restrict__ feat4,
                                      const float* __restrict__ dinv_out,
                                      float4* __restrict__ p0s4) {
    int i = blockIdx.x * 256 + threadIdx.x;  // dest float4 index over 8*50000*4
    if (i >= N_NODES * 32) return;
    int p = i / (N_NODES * 4);
    int rem = i - p * (N_NODES * 4);
    int n = rem >> 2, q = rem & 3;
    float s = dinv_out[n];
    float4 v = feat4[(size_t)n * 32 + p * 4 + q];
    float4 r;
    r.x = v.x * s; r.y = v.y * s; r.z = v.z * s; r.w = v.w * s;
    p0s4[i] = r;
}

// ---------------------------------------------------------------------------
// Column-sliced pull aggregation (L2-resident slice tables):
//   out[row] = scale[n] * sum_{s in Nin(n)} tab_slice[s]
// grid = NSLICE passes x NB_NODE blocks (pass-major); wave = 1 node;
// 4 neighbor-groups x 16 lanes, each group gathers one 64 B slice row.
// ---------------------------------------------------------------------------

__global__ __launch_bounds__(256) void agg_slice_kernel(
        const float* __restrict__ tab,       // [NSLICE][N_NODES][16] slice-major
        const int* __restrict__ csr_src,
        const int* __restrict__ row_off,
        const float* __restrict__ scale_vec,
        float* __restrict__ outbuf,
        const int* __restrict__ active, const int* __restrict__ nactp,
        int out_slice_major) {
    int pass = blockIdx.x / NB_NODE;
    int nb   = blockIdx.x - pass * NB_NODE;
    int wave = threadIdx.x >> 6;
    int lane = threadIdx.x & 63;
    int g = lane >> 4, f = lane & 15;
    int row = nb * 4 + wave;
    int nrows = nactp ? *nactp : N_NODES;
    if (row >= nrows) return;
    int n = active ? active[row] : row;
    int start = row_off[n], end = row_off[n + 1];
    const float* t = tab + (size_t)pass * N_NODES * 16;
    float acc = 0.f;
    for (int j0 = start; j0 < end; j0 += 64) {
        int jj = j0 + lane;
        int sv = (jj < end) ? csr_src[jj] : 0;
        int nj = min(64, end - j0);
        int itm = (nj + 3) >> 2;
#pragma unroll 4
        for (int i = 0; i < itm; ++i) {
            int idx = i * 4 + g;
            int s = __shfl(sv, idx, 64);
            if (idx < nj) acc += t[(size_t)s * 16 + f];
        }
    }
    acc += __shfl_xor(acc, 16, 64);
    acc += __shfl_xor(acc, 32, 64);
    if (lane < 16) {
        float r = acc * scale_vec[n];
        if (out_slice_major)
            outbuf[((size_t)pass * N_NODES + n) * 16 + f] = r;
        else
            outbuf[(size_t)n * D + pass * 16 + f] = r;
    }
}

// ---------------------------------------------------------------------------
// Row-major pull aggregation (label rows): out[row] = scale[n]*sum hs[s]
// ---------------------------------------------------------------------------

__global__ __launch_bounds__(256) void aggregate_kernel(
        const float* __restrict__ hs, const int* __restrict__ csr_src,
        const int* __restrict__ row_off, const float* __restrict__ scale_vec,
        float* __restrict__ outbuf, const int* __restrict__ nodeidx, int nrows) {
    int wave = threadIdx.x >> 6;
    int lane = threadIdx.x & 63;
    int hw = lane >> 5, l32 = lane & 31;
    int row = blockIdx.x * 4 + wave;
    if (row >= nrows) return;
    int n = nodeidx ? nodeidx[row] : row;
    int start = row_off[n], end = row_off[n + 1];
    const float4* h4 = (const float4*)hs;
    float4 acc = make_float4(0.f, 0.f, 0.f, 0.f);
    for (int j0 = start; j0 < end; j0 += 64) {
        int jj = j0 + lane;
        int sv = (jj < end) ? csr_src[jj] : 0;
        int nj = min(64, end - j0);
#pragma unroll 4
        for (int i = 0; i < nj; i += 2) {
            int idx = i + hw;
            int s = __shfl(sv, idx, 64);
            if (idx < nj) {
                float4 hv = h4[(size_t)s * 32 + l32];
                acc.x += hv.x; acc.y += hv.y; acc.z += hv.z; acc.w += hv.w;
            }
        }
    }
    acc.x += __shfl_xor(acc.x, 32, 64);
    acc.y += __shfl_xor(acc.y, 32, 64);
    acc.z += __shfl_xor(acc.z, 32, 64);
    acc.w += __shfl_xor(acc.w, 32, 64);
    if (hw == 0) {
        float wi = scale_vec[n];
        float4 r;
        r.x = acc.x * wi; r.y = acc.y * wi; r.z = acc.z * wi; r.w = acc.w * wi;
        ((float4*)outbuf)[(size_t)row * 32 + l32] = r;
    }
}

// ---------------------------------------------------------------------------
// Small matmul (4096 rows): out[r][c] = sum_k in[r][k]*W[k][c] + brow[r]*b[c]
// ---------------------------------------------------------------------------

__global__ __launch_bounds__(256) void matmul16_kernel(
        const float* __restrict__ in, const float* __restrict__ W,
        const float* __restrict__ b, const float* __restrict__ brow,
        float* __restrict__ outbuf, int nrows) {
    int t = threadIdx.x;
    int tx = t & 15, ty = t >> 4;
    int r = blockIdx.x * 16 + ty;
    if (r >= nrows) return;

    const float4* in4 = (const float4*)in;
    const float4* W4 = (const float4*)W;

    float bs = brow ? brow[r] : 1.0f;
    float4 bv0 = ((const float4*)b)[tx * 2];
    float4 bv1 = ((const float4*)b)[tx * 2 + 1];

    float acc[8];
    acc[0] = bs * bv0.x; acc[1] = bs * bv0.y; acc[2] = bs * bv0.z; acc[3] = bs * bv0.w;
    acc[4] = bs * bv1.x; acc[5] = bs * bv1.y; acc[6] = bs * bv1.z; acc[7] = bs * bv1.w;

#pragma unroll 4
    for (int kb = 0; kb < 32; ++kb) {
        float4 a = in4[(size_t)r * 32 + kb];
        int k4 = kb * 4;
#define MM16_STEP(kk, comp)                                           \
        {                                                             \
            float4 w0 = W4[(size_t)(k4 + kk) * 32 + tx * 2];          \
            float4 w1 = W4[(size_t)(k4 + kk) * 32 + tx * 2 + 1];      \
            acc[0] = fmaf(a.comp, w0.x, acc[0]);                      \
            acc[1] = fmaf(a.comp, w0.y, acc[1]);                      \
            acc[2] = fmaf(a.comp, w0.z, acc[2]);                      \
            acc[3] = fmaf(a.comp, w0.w, acc[3]);                      \
            acc[4] = fmaf(a.comp, w1.x, acc[4]);                      \
            acc[5] = fmaf(a.comp, w1.y, acc[5]);                      \
            acc[6] = fmaf(a.comp, w1.z, acc[6]);                      \
            acc[7] = fmaf(a.comp, w1.w, acc[7]);                      \
        }
        MM16_STEP(0, x)
        MM16_STEP(1, y)
        MM16_STEP(2, z)
        MM16_STEP(3, w)
#undef MM16_STEP
    }

    float4 o0, o1;
    o0.x = acc[0]; o0.y = acc[1]; o0.z = acc[2]; o0.w = acc[3];
    o1.x = acc[4]; o1.y = acc[5]; o1.z = acc[6]; o1.w = acc[7];
    float4* op = (float4*)&outbuf[(size_t)r * D + tx * 8];
    op[0] = o0;
    op[1] = o1;
}

// ---------------------------------------------------------------------------

extern "C" void kernel_launch(void* const* d_in, const int* in_sizes, int n_in,
                              void* d_out, int out_size, void* d_ws, size_t ws_size,
                              hipStream_t stream) {
    const int* labels = (const int*)d_in[0];
    const int* src    = (const int*)d_in[1];
    const int* dst    = (const int*)d_in[2];
    const float* feat = (const float*)d_in[3];
    const float* W0   = (const float*)d_in[4];
    const float* b0   = (const float*)d_in[5];
    const float* W1   = (const float*)d_in[6];
    const float* b1   = (const float*)d_in[7];
    const float* W2   = (const float*)d_in[8];
    const float* b2   = (const float*)d_in[9];
    float* out = (float*)d_out;

    char* ws = (char*)d_ws;
    size_t off = 0;
    auto alloc = [&](size_t bytes) -> void* {
        void* p = ws + off;
        off = (off + bytes + 255) & ~(size_t)255;
        return p;
    };
    int* row_off    = (int*)alloc((N_NODES + 1) * 4);
    int* fpos       = (int*)alloc((N_NODES + 1) * 4);
    int* blocksums  = (int*)alloc(256 * 4);
    int* blockoffs  = (int*)alloc(256 * 4);
    int* csr_src    = (int*)alloc((size_t)N_EDGES * 4);
    int* cnt_in     = (int*)alloc(N_NODES * 4);
    int* flag       = (int*)alloc(N_NODES * 4);
    int* active     = (int*)alloc(N_NODES * 4);
    float* dinv_out = (float*)alloc(N_NODES * 4);
    float* dinv_in  = (float*)alloc(N_NODES * 4);
    float* dinv_io  = (float*)alloc(N_NODES * 4);
    float* u1       = (float*)alloc(N_NODES * 4);
    float* u1s      = (float*)alloc(N_NODES * 4);
    float* u2       = (float*)alloc(N_NODES * 4);
    float* u1l      = (float*)alloc(N_LABELS * 4);
    float* u2l      = (float*)alloc(N_LABELS * 4);
    float* BUF1 = (float*)alloc((size_t)N_NODES * D * 4);  // epos | p0s | p2
    float* BUF2 = (float*)alloc((size_t)N_NODES * D * 4);  // Hsrc | p1 | tbuf/z1/z2

    // aliases (lifetimes are strictly ordered on the stream):
    int* epos = (int*)BUF1;                    // dead after fill_csr; then p0s
    unsigned int* Hsrc = (unsigned int*)BUF2;  // dead after dinv; then p1
    float* p0s = BUF1;                         // dead after agg1
    float* p1  = BUF2;                         // dead after agg2
    float* p2  = BUF1;                         // row-major, written by agg2
    float* tbuf = BUF2;                        // after agg2, p1 dead
    float* z1   = BUF2 + (size_t)N_LABELS * D;
    float* z2   = BUF2 + (size_t)2 * N_LABELS * D;

    hipMemsetAsync(cnt_in, 0, N_NODES * 4, stream);
    hipMemsetAsync(flag, 0, N_NODES * 4, stream);

    const int nScanBlocks = (N_NODES + 255) / 256;  // 196

    src_hist_kernel<<<HB, 256, 0, stream>>>(src, Hsrc);
    count_kernel<<<(N_EDGES + 255) / 256, 256, 0, stream>>>(dst, cnt_in, epos);
    dinv_kernel<<<nScanBlocks, 256, 0, stream>>>(Hsrc, cnt_in, dinv_out, dinv_in, dinv_io);
    scan_blocks_kernel<<<nScanBlocks, 256, 0, stream>>>(cnt_in, row_off, blocksums);
    scan_top_kernel<<<1, 256, 0, stream>>>(blocksums, blockoffs, nScanBlocks);
    scan_add_kernel<<<nScanBlocks, 256, 0, stream>>>(row_off, blockoffs);
    fill_csr_kernel<<<(N_EDGES + 255) / 256, 256, 0, stream>>>(src, dst, row_off, epos, csr_src);

    // bias-propagation vectors (wave-parallel gathers)
    uvec_kernel<<<NB_NODE, 256, 0, stream>>>(csr_src, row_off, dinv_out, dinv_in, dinv_io, u1, u1s);
    uvec_kernel<<<NB_NODE, 256, 0, stream>>>(csr_src, row_off, u1s, dinv_in, nullptr, u2, nullptr);
    gatherl_kernel<<<(N_LABELS + 255) / 256, 256, 0, stream>>>(labels, u1, u2, u1l, u2l);

    // active set = srcs of label-row edges (what agg3 will gather)
    flag_kernel<<<(N_LABELS + 255) / 256, 256, 0, stream>>>(labels, row_off, csr_src, flag);
    scan_blocks_kernel<<<nScanBlocks, 256, 0, stream>>>(flag, fpos, blocksums);
    scan_top_kernel<<<1, 256, 0, stream>>>(blocksums, blockoffs, nScanBlocks);
    scan_add_kernel<<<nScanBlocks, 256, 0, stream>>>(fpos, blockoffs);
    compact_kernel<<<nScanBlocks, 256, 0, stream>>>(flag, fpos, active);

    // p0s = slice-major(Dout * feat)  (epos dead)
    prescale_slice_kernel<<<(N_NODES * 32 + 255) / 256, 256, 0, stream>>>(
        (const float4*)feat, dinv_out, (float4*)p0s);

    const int aggSliceGrid = NSLICE * NB_NODE;  // 100000 blocks, pass-major

    // p1 = Dio A p0s (slice-major out; Hsrc dead)
    agg_slice_kernel<<<aggSliceGrid, 256, 0, stream>>>(p0s, csr_src, row_off, dinv_io,
                                                       p1, nullptr, nullptr, 1);
    // p2 = Dio A p1, active rows only (row-major by node; p0s dead)
    agg_slice_kernel<<<aggSliceGrid, 256, 0, stream>>>(p1, csr_src, row_off, dinv_io,
                                                       p2, active, &fpos[N_NODES], 0);
    // t = Din (A p2)[labels] -> tbuf (p1 dead)
    aggregate_kernel<<<(N_LABELS + 3) / 4, 256, 0, stream>>>(p2, csr_src, row_off,
                                                             dinv_in, tbuf, labels, N_LABELS);

    // z1 = t@W0 + u2l*b0 ; z2 = z1@W1 + u1l*b1 ; out = z2@W2 + b2
    const int mmGrid = (N_LABELS + 15) / 16;  // 256 blocks
    matmul16_kernel<<<mmGrid, 256, 0, stream>>>(tbuf, W0, b0, u2l, z1, N_LABELS);
    matmul16_kernel<<<mmGrid, 256, 0, stream>>>(z1, W1, b1, u1l, z2, N_LABELS);
    matmul16_kernel<<<mmGrid, 256, 0, stream>>>(z2, W2, b2, nullptr, out, N_LABELS);
}

// Round 7
// 278.232 us; speedup vs baseline: 1.7392x; 1.7392x over previous
//
#include <hip/hip_runtime.h>

#define N_NODES 50000
#define N_EDGES 800000
#define D 128
#define N_LABELS 4096
#define HB 256           // histogram blocks
#define HWORDS 12500     // 50000/4 packed u8 counters per block (50 KB LDS)
#define COUNT_BLOCKS 3125
#define FILL_BLOCKS 3125
#define PRESCALE_BLOCKS 6250   // N_NODES*32 float4 / 256
#define UVEC_BLOCKS 12500      // 4 nodes per block
#define FLAG_BLOCKS 16         // 4096 labels / 256
#define COMPACT_BLOCKS 196

// ---------------------------------------------------------------------------
// K1: hetero {src out-degree LDS histogram | dst count + epos capture}
// ---------------------------------------------------------------------------

__global__ __launch_bounds__(256) void hist_count_kernel(
        const int* __restrict__ src, const int* __restrict__ dst,
        unsigned int* __restrict__ Hsrc, int* __restrict__ cnt_in,
        int* __restrict__ epos) {
    __shared__ unsigned int hist[HWORDS];
    int t = threadIdx.x;
    if (blockIdx.x < HB) {
        // histogram role
        for (int i = t; i < HWORDS; i += 256) hist[i] = 0;
        __syncthreads();
        int base = blockIdx.x * (N_EDGES / HB);
        int end = base + (N_EDGES / HB);
        for (int e = base + t; e < end; e += 256) {
            int n = src[e];
            atomicAdd(&hist[n >> 2], 1u << ((n & 3) * 8));
        }
        __syncthreads();
        unsigned int* outp = Hsrc + (size_t)blockIdx.x * HWORDS;
        for (int i = t; i < HWORDS; i += 256) outp[i] = hist[i];
    } else {
        // count role
        int e = (blockIdx.x - HB) * 256 + t;
        if (e < N_EDGES) epos[e] = atomicAdd(&cnt_in[dst[e]], 1);
    }
}

// ---------------------------------------------------------------------------
// K2: merge src partials + compute dinv vectors
// ---------------------------------------------------------------------------

__global__ void dinv_kernel(const unsigned int* __restrict__ Hsrc,
                            const int* __restrict__ cnt_in,
                            float* __restrict__ dinv_out, float* __restrict__ dinv_in,
                            float* __restrict__ dinv_io) {
    int n = blockIdx.x * 256 + threadIdx.x;
    if (n >= N_NODES) return;
    int w = n >> 2, sh = (n & 3) * 8;
    unsigned int s = 0;
#pragma unroll 8
    for (int b = 0; b < HB; ++b) s += (Hsrc[(size_t)b * HWORDS + w] >> sh) & 0xFFu;
    int co = (int)s;
    int ci = cnt_in[n];
    float do_ = (co > 0) ? 1.0f / sqrtf((float)co) : 0.0f;
    float di_ = (ci > 0) ? 1.0f / sqrtf((float)ci) : 0.0f;
    dinv_out[n] = do_;
    dinv_in[n] = di_;
    dinv_io[n] = do_ * di_;
}

// ---------------------------------------------------------------------------
// generic block scan (inclusive into out[i+1]; out[0]=0 via scan_add)
// ---------------------------------------------------------------------------

__global__ void scan_blocks_kernel(const int* __restrict__ cnt, int* __restrict__ outv,
                                   int* __restrict__ blocksums) {
    __shared__ int s[256];
    int t = threadIdx.x;
    int i = blockIdx.x * 256 + t;
    int v = (i < N_NODES) ? cnt[i] : 0;
    s[t] = v;
    __syncthreads();
    for (int offs = 1; offs < 256; offs <<= 1) {
        int add = (t >= offs) ? s[t - offs] : 0;
        __syncthreads();
        s[t] += add;
        __syncthreads();
    }
    if (i < N_NODES) outv[i + 1] = s[t];
    if (t == 255) blocksums[blockIdx.x] = s[255];
}

__global__ void scan_top_kernel(const int* __restrict__ blocksums, int* __restrict__ blockoffs,
                                int nblocks) {
    __shared__ int s[256];
    int t = threadIdx.x;
    int v = (t < nblocks) ? blocksums[t] : 0;
    s[t] = v;
    __syncthreads();
    for (int offs = 1; offs < 256; offs <<= 1) {
        int add = (t >= offs) ? s[t - offs] : 0;
        __syncthreads();
        s[t] += add;
        __syncthreads();
    }
    blockoffs[t] = s[t] - v;  // exclusive
}

__global__ void scan_add_kernel(int* __restrict__ outv, const int* __restrict__ blockoffs) {
    int i = blockIdx.x * 256 + threadIdx.x;
    if (i < N_NODES) outv[i + 1] += blockoffs[blockIdx.x];
    if (i == 0) outv[0] = 0;
}

// ---------------------------------------------------------------------------
// K6: hetero {fill CSR scatter | prescale p0 = dinv_out * feat (row-major)}
// ---------------------------------------------------------------------------

__global__ __launch_bounds__(256) void fill_prescale_kernel(
        const int* __restrict__ src, const int* __restrict__ dst,
        const int* __restrict__ row_off, const int* __restrict__ epos,
        int* __restrict__ csr_src,
        const float4* __restrict__ feat4, const float* __restrict__ dinv_out,
        float4* __restrict__ p04) {
    int t = threadIdx.x;
    if (blockIdx.x < FILL_BLOCKS) {
        int e = blockIdx.x * 256 + t;
        if (e < N_EDGES) {
            int d = dst[e];
            csr_src[row_off[d] + epos[e]] = src[e];
        }
    } else {
        int i = (blockIdx.x - FILL_BLOCKS) * 256 + t;  // float4 index
        if (i < N_NODES * 32) {
            int n = i >> 5;
            float s = dinv_out[n];
            float4 v = feat4[i];
            float4 r;
            r.x = v.x * s; r.y = v.y * s; r.z = v.z * s; r.w = v.w * s;
            p04[i] = r;
        }
    }
}

// ---------------------------------------------------------------------------
// uvec body: o1[n] = s1[n]*sum g[s]; o2[n] = s2[n]*sum (optional)
// ---------------------------------------------------------------------------

__device__ __forceinline__ void uvec_body(int nb, int t,
        const int* __restrict__ csr_src, const int* __restrict__ row_off,
        const float* __restrict__ gvec, const float* __restrict__ s1,
        const float* __restrict__ s2, float* __restrict__ o1, float* __restrict__ o2) {
    int wave = t >> 6;
    int lane = t & 63;
    int n = nb * 4 + wave;
    if (n >= N_NODES) return;
    int start = row_off[n], end = row_off[n + 1];
    float a = 0.f;
    for (int j = start + lane; j < end; j += 64) a += gvec[csr_src[j]];
#pragma unroll
    for (int m = 32; m; m >>= 1) a += __shfl_xor(a, m, 64);
    if (lane == 0) {
        o1[n] = s1[n] * a;
        if (o2) o2[n] = s2[n] * a;
    }
}

// K7: hetero {uvec1 | flag label-edge sources}
__global__ __launch_bounds__(256) void uvec1_flag_kernel(
        const int* __restrict__ csr_src, const int* __restrict__ row_off,
        const float* __restrict__ dinv_out, const float* __restrict__ dinv_in,
        const float* __restrict__ dinv_io, float* __restrict__ u1, float* __restrict__ u1s,
        const int* __restrict__ labels, int* __restrict__ flag) {
    int t = threadIdx.x;
    if (blockIdx.x < UVEC_BLOCKS) {
        uvec_body(blockIdx.x, t, csr_src, row_off, dinv_out, dinv_in, dinv_io, u1, u1s);
    } else {
        int i = (blockIdx.x - UVEC_BLOCKS) * 256 + t;
        if (i < N_LABELS) {
            int n = labels[i];
            int a = row_off[n], bnd = row_off[n + 1];
            for (int j = a; j < bnd; ++j) flag[csr_src[j]] = 1;
        }
    }
}

// K11: hetero {uvec2 | compact active list}
__global__ __launch_bounds__(256) void uvec2_compact_kernel(
        const int* __restrict__ csr_src, const int* __restrict__ row_off,
        const float* __restrict__ u1s, const float* __restrict__ dinv_in,
        float* __restrict__ u2,
        const int* __restrict__ flag, const int* __restrict__ fpos,
        int* __restrict__ active) {
    int t = threadIdx.x;
    if (blockIdx.x < UVEC_BLOCKS) {
        uvec_body(blockIdx.x, t, csr_src, row_off, u1s, dinv_in, nullptr, u2, nullptr);
    } else {
        int n = (blockIdx.x - UVEC_BLOCKS) * 256 + t;
        if (n < N_NODES && flag[n]) active[fpos[n]] = n;
    }
}

// ---------------------------------------------------------------------------
// Row-major pull aggregation: out[row] = scale[n] * sum_{s in Nin(n)} hs[s]
// one wave per row; half-waves take alternate neighbors, float4/lane
// ---------------------------------------------------------------------------

__device__ __forceinline__ void agg_row_body(const float4* __restrict__ h4,
                                             const int* __restrict__ csr_src,
                                             int start, int end, int lane, int hw, int l32,
                                             float4& acc) {
    for (int j0 = start; j0 < end; j0 += 64) {
        int jj = j0 + lane;
        int sv = (jj < end) ? csr_src[jj] : 0;
        int nj = min(64, end - j0);
#pragma unroll 4
        for (int i = 0; i < nj; i += 2) {
            int idx = i + hw;
            int s = __shfl(sv, idx, 64);
            if (idx < nj) {
                float4 hv = h4[(size_t)s * 32 + l32];
                acc.x += hv.x; acc.y += hv.y; acc.z += hv.z; acc.w += hv.w;
            }
        }
    }
}

// nodeidx: optional row->node map; out row index = row
__global__ __launch_bounds__(256) void aggregate_kernel(
        const float* __restrict__ hs, const int* __restrict__ csr_src,
        const int* __restrict__ row_off, const float* __restrict__ scale_vec,
        float* __restrict__ outbuf, const int* __restrict__ nodeidx, int nrows) {
    int wave = threadIdx.x >> 6;
    int lane = threadIdx.x & 63;
    int hw = lane >> 5, l32 = lane & 31;
    int row = blockIdx.x * 4 + wave;
    if (row >= nrows) return;
    int n = nodeidx ? nodeidx[row] : row;
    float4 acc = make_float4(0.f, 0.f, 0.f, 0.f);
    agg_row_body((const float4*)hs, csr_src, row_off[n], row_off[n + 1], lane, hw, l32, acc);
    acc.x += __shfl_xor(acc.x, 32, 64);
    acc.y += __shfl_xor(acc.y, 32, 64);
    acc.z += __shfl_xor(acc.z, 32, 64);
    acc.w += __shfl_xor(acc.w, 32, 64);
    if (hw == 0) {
        float wi = scale_vec[n];
        float4 r;
        r.x = acc.x * wi; r.y = acc.y * wi; r.z = acc.z * wi; r.w = acc.w * wi;
        ((float4*)outbuf)[(size_t)row * 32 + l32] = r;
    }
}

// active-list variant: writes by node id
__global__ __launch_bounds__(256) void aggregate_active_kernel(
        const float* __restrict__ hs, const int* __restrict__ csr_src,
        const int* __restrict__ row_off, const float* __restrict__ scale_vec,
        float* __restrict__ outbuf, const int* __restrict__ active,
        const int* __restrict__ nactp) {
    int wave = threadIdx.x >> 6;
    int lane = threadIdx.x & 63;
    int hw = lane >> 5, l32 = lane & 31;
    int row = blockIdx.x * 4 + wave;
    if (row >= *nactp) return;
    int n = active[row];
    float4 acc = make_float4(0.f, 0.f, 0.f, 0.f);
    agg_row_body((const float4*)hs, csr_src, row_off[n], row_off[n + 1], lane, hw, l32, acc);
    acc.x += __shfl_xor(acc.x, 32, 64);
    acc.y += __shfl_xor(acc.y, 32, 64);
    acc.z += __shfl_xor(acc.z, 32, 64);
    acc.w += __shfl_xor(acc.w, 32, 64);
    if (hw == 0) {
        float wi = scale_vec[n];
        float4 r;
        r.x = acc.x * wi; r.y = acc.y * wi; r.z = acc.z * wi; r.w = acc.w * wi;
        ((float4*)outbuf)[(size_t)n * 32 + l32] = r;
    }
}

// ---------------------------------------------------------------------------
// Small matmul (4096 rows): out[r][c] = sum_k in[r][k]*W[k][c] + brow[bidx[r]]*b[c]
// ---------------------------------------------------------------------------

__global__ __launch_bounds__(256) void matmul16_kernel(
        const float* __restrict__ in, const float* __restrict__ W,
        const float* __restrict__ b, const float* __restrict__ brow,
        const int* __restrict__ bidx, float* __restrict__ outbuf, int nrows) {
    int t = threadIdx.x;
    int tx = t & 15, ty = t >> 4;
    int r = blockIdx.x * 16 + ty;
    if (r >= nrows) return;

    const float4* in4 = (const float4*)in;
    const float4* W4 = (const float4*)W;

    float bs = 1.0f;
    if (brow) bs = bidx ? brow[bidx[r]] : brow[r];
    float4 bv0 = ((const float4*)b)[tx * 2];
    float4 bv1 = ((const float4*)b)[tx * 2 + 1];

    float acc[8];
    acc[0] = bs * bv0.x; acc[1] = bs * bv0.y; acc[2] = bs * bv0.z; acc[3] = bs * bv0.w;
    acc[4] = bs * bv1.x; acc[5] = bs * bv1.y; acc[6] = bs * bv1.z; acc[7] = bs * bv1.w;

#pragma unroll 4
    for (int kb = 0; kb < 32; ++kb) {
        float4 a = in4[(size_t)r * 32 + kb];
        int k4 = kb * 4;
#define MM16_STEP(kk, comp)                                           \
        {                                                             \
            float4 w0 = W4[(size_t)(k4 + kk) * 32 + tx * 2];          \
            float4 w1 = W4[(size_t)(k4 + kk) * 32 + tx * 2 + 1];      \
            acc[0] = fmaf(a.comp, w0.x, acc[0]);                      \
            acc[1] = fmaf(a.comp, w0.y, acc[1]);                      \
            acc[2] = fmaf(a.comp, w0.z, acc[2]);                      \
            acc[3] = fmaf(a.comp, w0.w, acc[3]);                      \
            acc[4] = fmaf(a.comp, w1.x, acc[4]);                      \
            acc[5] = fmaf(a.comp, w1.y, acc[5]);                      \
            acc[6] = fmaf(a.comp, w1.z, acc[6]);                      \
            acc[7] = fmaf(a.comp, w1.w, acc[7]);                      \
        }
        MM16_STEP(0, x)
        MM16_STEP(1, y)
        MM16_STEP(2, z)
        MM16_STEP(3, w)
#undef MM16_STEP
    }

    float4 o0, o1;
    o0.x = acc[0]; o0.y = acc[1]; o0.z = acc[2]; o0.w = acc[3];
    o1.x = acc[4]; o1.y = acc[5]; o1.z = acc[6]; o1.w = acc[7];
    float4* op = (float4*)&outbuf[(size_t)r * D + tx * 8];
    op[0] = o0;
    op[1] = o1;
}

// ---------------------------------------------------------------------------

extern "C" void kernel_launch(void* const* d_in, const int* in_sizes, int n_in,
                              void* d_out, int out_size, void* d_ws, size_t ws_size,
                              hipStream_t stream) {
    const int* labels = (const int*)d_in[0];
    const int* src    = (const int*)d_in[1];
    const int* dst    = (const int*)d_in[2];
    const float* feat = (const float*)d_in[3];
    const float* W0   = (const float*)d_in[4];
    const float* b0   = (const float*)d_in[5];
    const float* W1   = (const float*)d_in[6];
    const float* b1   = (const float*)d_in[7];
    const float* W2   = (const float*)d_in[8];
    const float* b2   = (const float*)d_in[9];
    float* out = (float*)d_out;

    char* ws = (char*)d_ws;
    size_t off = 0;
    auto alloc = [&](size_t bytes) -> void* {
        void* p = ws + off;
        off = (off + bytes + 255) & ~(size_t)255;
        return p;
    };
    int* row_off    = (int*)alloc((N_NODES + 1) * 4);
    int* fpos       = (int*)alloc((N_NODES + 1) * 4);
    int* blocksums  = (int*)alloc(256 * 4);
    int* blockoffs  = (int*)alloc(256 * 4);
    int* csr_src    = (int*)alloc((size_t)N_EDGES * 4);
    int* epos       = (int*)alloc((size_t)N_EDGES * 4);
    int* cnt_in     = (int*)alloc(N_NODES * 4);
    int* flag       = (int*)alloc(N_NODES * 4);
    int* active     = (int*)alloc(N_NODES * 4);
    float* dinv_out = (float*)alloc(N_NODES * 4);
    float* dinv_in  = (float*)alloc(N_NODES * 4);
    float* dinv_io  = (float*)alloc(N_NODES * 4);
    float* u1       = (float*)alloc(N_NODES * 4);
    float* u1s      = (float*)alloc(N_NODES * 4);
    float* u2       = (float*)alloc(N_NODES * 4);
    float* BUF1 = (float*)alloc((size_t)N_NODES * D * 4);  // p0 | p2
    float* BUF2 = (float*)alloc((size_t)N_NODES * D * 4);  // Hsrc | p1 | tbuf/z1/z2

    // aliases (stream-ordered lifetimes):
    unsigned int* Hsrc = (unsigned int*)BUF2;        // dead after dinv; p1 written later
    float* p0 = BUF1;                                // written by K6, read by agg1
    float* p1 = BUF2;                                // written by agg1, read by agg2
    float* p2 = BUF1;                                // p0 dead after agg1
    float* tbuf = BUF2;                              // p1 dead after agg2
    float* z1 = BUF2 + (size_t)N_LABELS * D;
    float* z2 = BUF2 + (size_t)2 * N_LABELS * D;

    hipMemsetAsync(cnt_in, 0, N_NODES * 4, stream);
    hipMemsetAsync(flag, 0, N_NODES * 4, stream);

    const int nScanBlocks = (N_NODES + 255) / 256;  // 196

    // K1: hist + count
    hist_count_kernel<<<HB + COUNT_BLOCKS, 256, 0, stream>>>(src, dst, Hsrc, cnt_in, epos);
    // K2: dinv
    dinv_kernel<<<nScanBlocks, 256, 0, stream>>>(Hsrc, cnt_in, dinv_out, dinv_in, dinv_io);
    // K3-5: scan row_off
    scan_blocks_kernel<<<nScanBlocks, 256, 0, stream>>>(cnt_in, row_off, blocksums);
    scan_top_kernel<<<1, 256, 0, stream>>>(blocksums, blockoffs, nScanBlocks);
    scan_add_kernel<<<nScanBlocks, 256, 0, stream>>>(row_off, blockoffs);
    // K6: fill + prescale
    fill_prescale_kernel<<<FILL_BLOCKS + PRESCALE_BLOCKS, 256, 0, stream>>>(
        src, dst, row_off, epos, csr_src, (const float4*)feat, dinv_out, (float4*)p0);
    // K7: uvec1 + flag
    uvec1_flag_kernel<<<UVEC_BLOCKS + FLAG_BLOCKS, 256, 0, stream>>>(
        csr_src, row_off, dinv_out, dinv_in, dinv_io, u1, u1s, labels, flag);
    // K8-10: scan fpos
    scan_blocks_kernel<<<nScanBlocks, 256, 0, stream>>>(flag, fpos, blocksums);
    scan_top_kernel<<<1, 256, 0, stream>>>(blocksums, blockoffs, nScanBlocks);
    scan_add_kernel<<<nScanBlocks, 256, 0, stream>>>(fpos, blockoffs);
    // K11: uvec2 + compact
    uvec2_compact_kernel<<<UVEC_BLOCKS + COMPACT_BLOCKS, 256, 0, stream>>>(
        csr_src, row_off, u1s, dinv_in, u2, flag, fpos, active);

    // K12: p1 = Dio A p0
    aggregate_kernel<<<UVEC_BLOCKS, 256, 0, stream>>>(p0, csr_src, row_off, dinv_io,
                                                      p1, nullptr, N_NODES);
    // K13: p2 = Dio A p1 (active rows, write-by-node)
    aggregate_active_kernel<<<UVEC_BLOCKS, 256, 0, stream>>>(p1, csr_src, row_off, dinv_io,
                                                             p2, active, &fpos[N_NODES]);
    // K14: t = Din (A p2)[labels]
    aggregate_kernel<<<(N_LABELS + 3) / 4, 256, 0, stream>>>(p2, csr_src, row_off,
                                                             dinv_in, tbuf, labels, N_LABELS);

    // K15-17: z1 = t@W0 + u2[labels]*b0 ; z2 = z1@W1 + u1[labels]*b1 ; out = z2@W2 + b2
    const int mmGrid = (N_LABELS + 15) / 16;  // 256 blocks
    matmul16_kernel<<<mmGrid, 256, 0, stream>>>(tbuf, W0, b0, u2, labels, z1, N_LABELS);
    matmul16_kernel<<<mmGrid, 256, 0, stream>>>(z1, W1, b1, u1, labels, z2, N_LABELS);
    matmul16_kernel<<<mmGrid, 256, 0, stream>>>(z2, W2, b2, nullptr, nullptr, out, N_LABELS);
}

// Round 9
// 275.552 us; speedup vs baseline: 1.7561x; 1.0097x over previous
//
#include <hip/hip_runtime.h>

#define N_NODES 50000
#define N_EDGES 800000
#define D 128
#define N_LABELS 4096
#define HB 256           // histogram blocks
#define HWORDS 12500     // 50000/4 packed u8 counters per block (50 KB LDS)
#define COUNT_BLOCKS 3125
#define FILL_BLOCKS 3125
#define PRESCALE_BLOCKS 6250   // N_NODES*32 float4 / 256
#define UVEC_BLOCKS 12500      // 4 nodes per block
#define FLAG_BLOCKS 16         // 4096 labels / 256
#define COMPACT_BLOCKS 196

// ---------------------------------------------------------------------------
// K1: hetero {src out-degree LDS histogram | dst count + epos capture}
// ---------------------------------------------------------------------------

__global__ __launch_bounds__(256) void hist_count_kernel(
        const int* __restrict__ src, const int* __restrict__ dst,
        unsigned int* __restrict__ Hsrc, int* __restrict__ cnt_in,
        int* __restrict__ epos) {
    __shared__ unsigned int hist[HWORDS];
    int t = threadIdx.x;
    if (blockIdx.x < HB) {
        for (int i = t; i < HWORDS; i += 256) hist[i] = 0;
        __syncthreads();
        int base = blockIdx.x * (N_EDGES / HB);
        int end = base + (N_EDGES / HB);
        for (int e = base + t; e < end; e += 256) {
            int n = src[e];
            atomicAdd(&hist[n >> 2], 1u << ((n & 3) * 8));
        }
        __syncthreads();
        unsigned int* outp = Hsrc + (size_t)blockIdx.x * HWORDS;
        for (int i = t; i < HWORDS; i += 256) outp[i] = hist[i];
    } else {
        int e = (blockIdx.x - HB) * 256 + t;
        if (e < N_EDGES) epos[e] = atomicAdd(&cnt_in[dst[e]], 1);
    }
}

// ---------------------------------------------------------------------------
// K2: merge src partials + compute dinv vectors
// ---------------------------------------------------------------------------

__global__ void dinv_kernel(const unsigned int* __restrict__ Hsrc,
                            const int* __restrict__ cnt_in,
                            float* __restrict__ dinv_out, float* __restrict__ dinv_in,
                            float* __restrict__ dinv_io) {
    int n = blockIdx.x * 256 + threadIdx.x;
    if (n >= N_NODES) return;
    int w = n >> 2, sh = (n & 3) * 8;
    unsigned int s = 0;
#pragma unroll 8
    for (int b = 0; b < HB; ++b) s += (Hsrc[(size_t)b * HWORDS + w] >> sh) & 0xFFu;
    int co = (int)s;
    int ci = cnt_in[n];
    float do_ = (co > 0) ? 1.0f / sqrtf((float)co) : 0.0f;
    float di_ = (ci > 0) ? 1.0f / sqrtf((float)ci) : 0.0f;
    dinv_out[n] = do_;
    dinv_in[n] = di_;
    dinv_io[n] = do_ * di_;
}

// ---------------------------------------------------------------------------
// generic block scan (inclusive into out[i+1]; out[0]=0 via scan_add)
// ---------------------------------------------------------------------------

__global__ void scan_blocks_kernel(const int* __restrict__ cnt, int* __restrict__ outv,
                                   int* __restrict__ blocksums) {
    __shared__ int s[256];
    int t = threadIdx.x;
    int i = blockIdx.x * 256 + t;
    int v = (i < N_NODES) ? cnt[i] : 0;
    s[t] = v;
    __syncthreads();
    for (int offs = 1; offs < 256; offs <<= 1) {
        int add = (t >= offs) ? s[t - offs] : 0;
        __syncthreads();
        s[t] += add;
        __syncthreads();
    }
    if (i < N_NODES) outv[i + 1] = s[t];
    if (t == 255) blocksums[blockIdx.x] = s[255];
}

__global__ void scan_top_kernel(const int* __restrict__ blocksums, int* __restrict__ blockoffs,
                                int nblocks) {
    __shared__ int s[256];
    int t = threadIdx.x;
    int v = (t < nblocks) ? blocksums[t] : 0;
    s[t] = v;
    __syncthreads();
    for (int offs = 1; offs < 256; offs <<= 1) {
        int add = (t >= offs) ? s[t - offs] : 0;
        __syncthreads();
        s[t] += add;
        __syncthreads();
    }
    blockoffs[t] = s[t] - v;  // exclusive
}

__global__ void scan_add_kernel(int* __restrict__ outv, const int* __restrict__ blockoffs) {
    int i = blockIdx.x * 256 + threadIdx.x;
    if (i < N_NODES) outv[i + 1] += blockoffs[blockIdx.x];
    if (i == 0) outv[0] = 0;
}

// ---------------------------------------------------------------------------
// K6: hetero {fill CSR scatter | prescale p0 = dinv_out * feat (row-major)}
// ---------------------------------------------------------------------------

__global__ __launch_bounds__(256) void fill_prescale_kernel(
        const int* __restrict__ src, const int* __restrict__ dst,
        const int* __restrict__ row_off, const int* __restrict__ epos,
        int* __restrict__ csr_src,
        const float4* __restrict__ feat4, const float* __restrict__ dinv_out,
        float4* __restrict__ p04) {
    int t = threadIdx.x;
    if (blockIdx.x < FILL_BLOCKS) {
        int e = blockIdx.x * 256 + t;
        if (e < N_EDGES) {
            int d = dst[e];
            csr_src[row_off[d] + epos[e]] = src[e];
        }
    } else {
        int i = (blockIdx.x - FILL_BLOCKS) * 256 + t;  // float4 index
        if (i < N_NODES * 32) {
            int n = i >> 5;
            float s = dinv_out[n];
            float4 v = feat4[i];
            float4 r;
            r.x = v.x * s; r.y = v.y * s; r.z = v.z * s; r.w = v.w * s;
            p04[i] = r;
        }
    }
}

// ---------------------------------------------------------------------------
// uvec body: o1[n] = s1[n]*sum g[s]; o2[n] = s2[n]*sum (optional)
// ---------------------------------------------------------------------------

__device__ __forceinline__ void uvec_body(int nb, int t,
        const int* __restrict__ csr_src, const int* __restrict__ row_off,
        const float* __restrict__ gvec, const float* __restrict__ s1,
        const float* __restrict__ s2, float* __restrict__ o1, float* __restrict__ o2) {
    int wave = t >> 6;
    int lane = t & 63;
    int n = nb * 4 + wave;
    if (n >= N_NODES) return;
    int start = row_off[n], end = row_off[n + 1];
    float a = 0.f;
    for (int j = start + lane; j < end; j += 64) a += gvec[csr_src[j]];
#pragma unroll
    for (int m = 32; m; m >>= 1) a += __shfl_xor(a, m, 64);
    if (lane == 0) {
        o1[n] = s1[n] * a;
        if (o2) o2[n] = s2[n] * a;
    }
}

// K7: hetero {uvec1 | flag label-edge sources}
__global__ __launch_bounds__(256) void uvec1_flag_kernel(
        const int* __restrict__ csr_src, const int* __restrict__ row_off,
        const float* __restrict__ dinv_out, const float* __restrict__ dinv_in,
        const float* __restrict__ dinv_io, float* __restrict__ u1, float* __restrict__ u1s,
        const int* __restrict__ labels, int* __restrict__ flag) {
    int t = threadIdx.x;
    if (blockIdx.x < UVEC_BLOCKS) {
        uvec_body(blockIdx.x, t, csr_src, row_off, dinv_out, dinv_in, dinv_io, u1, u1s);
    } else {
        int i = (blockIdx.x - UVEC_BLOCKS) * 256 + t;
        if (i < N_LABELS) {
            int n = labels[i];
            int a = row_off[n], bnd = row_off[n + 1];
            for (int j = a; j < bnd; ++j) flag[csr_src[j]] = 1;
        }
    }
}

// K11: hetero {uvec2 | compact active list}
__global__ __launch_bounds__(256) void uvec2_compact_kernel(
        const int* __restrict__ csr_src, const int* __restrict__ row_off,
        const float* __restrict__ u1s, const float* __restrict__ dinv_in,
        float* __restrict__ u2,
        const int* __restrict__ flag, const int* __restrict__ fpos,
        int* __restrict__ active) {
    int t = threadIdx.x;
    if (blockIdx.x < UVEC_BLOCKS) {
        uvec_body(blockIdx.x, t, csr_src, row_off, u1s, dinv_in, nullptr, u2, nullptr);
    } else {
        int n = (blockIdx.x - UVEC_BLOCKS) * 256 + t;
        if (n < N_NODES && flag[n]) active[fpos[n]] = n;
    }
}

// ---------------------------------------------------------------------------
// Row-major pull aggregation: out[row] = scale[n] * sum_{s in Nin(n)} hs[s]
// one wave per row; half-waves take alternate neighbors, float4/lane.
// Inner loop: WAVE-UNIFORM batches of 8 neighbors (4 per half-wave) so every
// __shfl executes with all 64 lanes active (shfl from an exec-masked lane is
// undefined on CDNA — the R8 bug); uniform-bound guarded tail.
// ---------------------------------------------------------------------------

__device__ __forceinline__ void agg_row_body(const float4* __restrict__ h4,
                                             const int* __restrict__ csr_src,
                                             int start, int end, int lane, int hw, int l32,
                                             float4& accOut) {
    float4 a0 = make_float4(0.f, 0.f, 0.f, 0.f);
    float4 a1 = a0, a2 = a0, a3 = a0;
    for (int j0 = start; j0 < end; j0 += 64) {
        int jj = j0 + lane;
        int sv = (jj < end) ? csr_src[jj] : 0;
        int nj = min(64, end - j0);
        int i = 0;
        // uniform batches: 8 neighbors (idx i..i+7), 4 per half-wave, all in-range
        for (; i + 8 <= nj; i += 8) {
            int s0 = __shfl(sv, i + hw, 64);
            int s1 = __shfl(sv, i + 2 + hw, 64);
            int s2 = __shfl(sv, i + 4 + hw, 64);
            int s3 = __shfl(sv, i + 6 + hw, 64);
            float4 h0 = h4[(size_t)s0 * 32 + l32];
            float4 h1 = h4[(size_t)s1 * 32 + l32];
            float4 h2 = h4[(size_t)s2 * 32 + l32];
            float4 h3 = h4[(size_t)s3 * 32 + l32];
            a0.x += h0.x; a0.y += h0.y; a0.z += h0.z; a0.w += h0.w;
            a1.x += h1.x; a1.y += h1.y; a1.z += h1.z; a1.w += h1.w;
            a2.x += h2.x; a2.y += h2.y; a2.z += h2.z; a2.w += h2.w;
            a3.x += h3.x; a3.y += h3.y; a3.z += h3.z; a3.w += h3.w;
        }
        // uniform-bound tail, guard only the load (R7-proven pattern)
        for (; i < nj; i += 2) {
            int idx = i + hw;
            int s = __shfl(sv, idx, 64);
            if (idx < nj) {
                float4 h0 = h4[(size_t)s * 32 + l32];
                a0.x += h0.x; a0.y += h0.y; a0.z += h0.z; a0.w += h0.w;
            }
        }
    }
    accOut.x = (a0.x + a1.x) + (a2.x + a3.x);
    accOut.y = (a0.y + a1.y) + (a2.y + a3.y);
    accOut.z = (a0.z + a1.z) + (a2.z + a3.z);
    accOut.w = (a0.w + a1.w) + (a2.w + a3.w);
}

// nodeidx: optional row->node map; out row index = row
__global__ __launch_bounds__(256) void aggregate_kernel(
        const float* __restrict__ hs, const int* __restrict__ csr_src,
        const int* __restrict__ row_off, const float* __restrict__ scale_vec,
        float* __restrict__ outbuf, const int* __restrict__ nodeidx, int nrows) {
    int wave = threadIdx.x >> 6;
    int lane = threadIdx.x & 63;
    int hw = lane >> 5, l32 = lane & 31;
    int row = blockIdx.x * 4 + wave;
    if (row >= nrows) return;
    int n = nodeidx ? nodeidx[row] : row;
    float4 acc;
    agg_row_body((const float4*)hs, csr_src, row_off[n], row_off[n + 1], lane, hw, l32, acc);
    acc.x += __shfl_xor(acc.x, 32, 64);
    acc.y += __shfl_xor(acc.y, 32, 64);
    acc.z += __shfl_xor(acc.z, 32, 64);
    acc.w += __shfl_xor(acc.w, 32, 64);
    if (hw == 0) {
        float wi = scale_vec[n];
        float4 r;
        r.x = acc.x * wi; r.y = acc.y * wi; r.z = acc.z * wi; r.w = acc.w * wi;
        ((float4*)outbuf)[(size_t)row * 32 + l32] = r;
    }
}

// active-list variant: writes by node id
__global__ __launch_bounds__(256) void aggregate_active_kernel(
        const float* __restrict__ hs, const int* __restrict__ csr_src,
        const int* __restrict__ row_off, const float* __restrict__ scale_vec,
        float* __restrict__ outbuf, const int* __restrict__ active,
        const int* __restrict__ nactp) {
    int wave = threadIdx.x >> 6;
    int lane = threadIdx.x & 63;
    int hw = lane >> 5, l32 = lane & 31;
    int row = blockIdx.x * 4 + wave;
    if (row >= *nactp) return;
    int n = active[row];
    float4 acc;
    agg_row_body((const float4*)hs, csr_src, row_off[n], row_off[n + 1], lane, hw, l32, acc);
    acc.x += __shfl_xor(acc.x, 32, 64);
    acc.y += __shfl_xor(acc.y, 32, 64);
    acc.z += __shfl_xor(acc.z, 32, 64);
    acc.w += __shfl_xor(acc.w, 32, 64);
    if (hw == 0) {
        float wi = scale_vec[n];
        float4 r;
        r.x = acc.x * wi; r.y = acc.y * wi; r.z = acc.z * wi; r.w = acc.w * wi;
        ((float4*)outbuf)[(size_t)n * 32 + l32] = r;
    }
}

// ---------------------------------------------------------------------------
// Small matmul (4096 rows): out[r][c] = sum_k in[r][k]*W[k][c] + brow[bidx[r]]*b[c]
// ---------------------------------------------------------------------------

__global__ __launch_bounds__(256) void matmul16_kernel(
        const float* __restrict__ in, const float* __restrict__ W,
        const float* __restrict__ b, const float* __restrict__ brow,
        const int* __restrict__ bidx, float* __restrict__ outbuf, int nrows) {
    int t = threadIdx.x;
    int tx = t & 15, ty = t >> 4;
    int r = blockIdx.x * 16 + ty;
    if (r >= nrows) return;

    const float4* in4 = (const float4*)in;
    const float4* W4 = (const float4*)W;

    float bs = 1.0f;
    if (brow) bs = bidx ? brow[bidx[r]] : brow[r];
    float4 bv0 = ((const float4*)b)[tx * 2];
    float4 bv1 = ((const float4*)b)[tx * 2 + 1];

    float acc[8];
    acc[0] = bs * bv0.x; acc[1] = bs * bv0.y; acc[2] = bs * bv0.z; acc[3] = bs * bv0.w;
    acc[4] = bs * bv1.x; acc[5] = bs * bv1.y; acc[6] = bs * bv1.z; acc[7] = bs * bv1.w;

#pragma unroll 4
    for (int kb = 0; kb < 32; ++kb) {
        float4 a = in4[(size_t)r * 32 + kb];
        int k4 = kb * 4;
#define MM16_STEP(kk, comp)                                           \
        {                                                             \
            float4 w0 = W4[(size_t)(k4 + kk) * 32 + tx * 2];          \
            float4 w1 = W4[(size_t)(k4 + kk) * 32 + tx * 2 + 1];      \
            acc[0] = fmaf(a.comp, w0.x, acc[0]);                      \
            acc[1] = fmaf(a.comp, w0.y, acc[1]);                      \
            acc[2] = fmaf(a.comp, w0.z, acc[2]);                      \
            acc[3] = fmaf(a.comp, w0.w, acc[3]);                      \
            acc[4] = fmaf(a.comp, w1.x, acc[4]);                      \
            acc[5] = fmaf(a.comp, w1.y, acc[5]);                      \
            acc[6] = fmaf(a.comp, w1.z, acc[6]);                      \
            acc[7] = fmaf(a.comp, w1.w, acc[7]);                      \
        }
        MM16_STEP(0, x)
        MM16_STEP(1, y)
        MM16_STEP(2, z)
        MM16_STEP(3, w)
#undef MM16_STEP
    }

    float4 o0, o1;
    o0.x = acc[0]; o0.y = acc[1]; o0.z = acc[2]; o0.w = acc[3];
    o1.x = acc[4]; o1.y = acc[5]; o1.z = acc[6]; o1.w = acc[7];
    float4* op = (float4*)&outbuf[(size_t)r * D + tx * 8];
    op[0] = o0;
    op[1] = o1;
}

// ---------------------------------------------------------------------------

extern "C" void kernel_launch(void* const* d_in, const int* in_sizes, int n_in,
                              void* d_out, int out_size, void* d_ws, size_t ws_size,
                              hipStream_t stream) {
    const int* labels = (const int*)d_in[0];
    const int* src    = (const int*)d_in[1];
    const int* dst    = (const int*)d_in[2];
    const float* feat = (const float*)d_in[3];
    const float* W0   = (const float*)d_in[4];
    const float* b0   = (const float*)d_in[5];
    const float* W1   = (const float*)d_in[6];
    const float* b1   = (const float*)d_in[7];
    const float* W2   = (const float*)d_in[8];
    const float* b2   = (const float*)d_in[9];
    float* out = (float*)d_out;

    char* ws = (char*)d_ws;
    size_t off = 0;
    auto alloc = [&](size_t bytes) -> void* {
        void* p = ws + off;
        off = (off + bytes + 255) & ~(size_t)255;
        return p;
    };
    int* row_off    = (int*)alloc((N_NODES + 1) * 4);
    int* fpos       = (int*)alloc((N_NODES + 1) * 4);
    int* blocksums  = (int*)alloc(256 * 4);
    int* blockoffs  = (int*)alloc(256 * 4);
    int* csr_src    = (int*)alloc((size_t)N_EDGES * 4);
    int* epos       = (int*)alloc((size_t)N_EDGES * 4);
    int* cnt_in     = (int*)alloc(N_NODES * 4);
    int* flag       = (int*)alloc(N_NODES * 4);
    int* active     = (int*)alloc(N_NODES * 4);
    float* dinv_out = (float*)alloc(N_NODES * 4);
    float* dinv_in  = (float*)alloc(N_NODES * 4);
    float* dinv_io  = (float*)alloc(N_NODES * 4);
    float* u1       = (float*)alloc(N_NODES * 4);
    float* u1s      = (float*)alloc(N_NODES * 4);
    float* u2       = (float*)alloc(N_NODES * 4);
    float* BUF1 = (float*)alloc((size_t)N_NODES * D * 4);  // p0 | p2
    float* BUF2 = (float*)alloc((size_t)N_NODES * D * 4);  // Hsrc | p1 | tbuf/z1/z2

    // aliases (stream-ordered lifetimes):
    unsigned int* Hsrc = (unsigned int*)BUF2;        // dead after dinv; p1 written later
    float* p0 = BUF1;                                // written by K6, read by agg1
    float* p1 = BUF2;                                // written by agg1, read by agg2
    float* p2 = BUF1;                                // p0 dead after agg1
    float* tbuf = BUF2;                              // p1 dead after agg2
    float* z1 = BUF2 + (size_t)N_LABELS * D;
    float* z2 = BUF2 + (size_t)2 * N_LABELS * D;

    hipMemsetAsync(cnt_in, 0, N_NODES * 4, stream);
    hipMemsetAsync(flag, 0, N_NODES * 4, stream);

    const int nScanBlocks = (N_NODES + 255) / 256;  // 196

    // K1: hist + count
    hist_count_kernel<<<HB + COUNT_BLOCKS, 256, 0, stream>>>(src, dst, Hsrc, cnt_in, epos);
    // K2: dinv
    dinv_kernel<<<nScanBlocks, 256, 0, stream>>>(Hsrc, cnt_in, dinv_out, dinv_in, dinv_io);
    // K3-5: scan row_off
    scan_blocks_kernel<<<nScanBlocks, 256, 0, stream>>>(cnt_in, row_off, blocksums);
    scan_top_kernel<<<1, 256, 0, stream>>>(blocksums, blockoffs, nScanBlocks);
    scan_add_kernel<<<nScanBlocks, 256, 0, stream>>>(row_off, blockoffs);
    // K6: fill + prescale
    fill_prescale_kernel<<<FILL_BLOCKS + PRESCALE_BLOCKS, 256, 0, stream>>>(
        src, dst, row_off, epos, csr_src, (const float4*)feat, dinv_out, (float4*)p0);
    // K7: uvec1 + flag
    uvec1_flag_kernel<<<UVEC_BLOCKS + FLAG_BLOCKS, 256, 0, stream>>>(
        csr_src, row_off, dinv_out, dinv_in, dinv_io, u1, u1s, labels, flag);
    // K8-10: scan fpos
    scan_blocks_kernel<<<nScanBlocks, 256, 0, stream>>>(flag, fpos, blocksums);
    scan_top_kernel<<<1, 256, 0, stream>>>(blocksums, blockoffs, nScanBlocks);
    scan_add_kernel<<<nScanBlocks, 256, 0, stream>>>(fpos, blockoffs);
    // K11: uvec2 + compact
    uvec2_compact_kernel<<<UVEC_BLOCKS + COMPACT_BLOCKS, 256, 0, stream>>>(
        csr_src, row_off, u1s, dinv_in, u2, flag, fpos, active);

    // K12: p1 = Dio A p0
    aggregate_kernel<<<UVEC_BLOCKS, 256, 0, stream>>>(p0, csr_src, row_off, dinv_io,
                                                      p1, nullptr, N_NODES);
    // K13: p2 = Dio A p1 (active rows, write-by-node)
    aggregate_active_kernel<<<UVEC_BLOCKS, 256, 0, stream>>>(p1, csr_src, row_off, dinv_io,
                                                             p2, active, &fpos[N_NODES]);
    // K14: t = Din (A p2)[labels]
    aggregate_kernel<<<(N_LABELS + 3) / 4, 256, 0, stream>>>(p2, csr_src, row_off,
                                                             dinv_in, tbuf, labels, N_LABELS);

    // K15-17: z1 = t@W0 + u2[labels]*b0 ; z2 = z1@W1 + u1[labels]*b1 ; out = z2@W2 + b2
    const int mmGrid = (N_LABELS + 15) / 16;  // 256 blocks
    matmul16_kernel<<<mmGrid, 256, 0, stream>>>(tbuf, W0, b0, u2, labels, z1, N_LABELS);
    matmul16_kernel<<<mmGrid, 256, 0, stream>>>(z1, W1, b1, u1, labels, z2, N_LABELS);
    matmul16_kernel<<<mmGrid, 256, 0, stream>>>(z2, W2, b2, nullptr, nullptr, out, N_LABELS);
}

// Round 10
// 257.280 us; speedup vs baseline: 1.8809x; 1.0710x over previous
//
#include <hip/hip_runtime.h>

#define N_NODES 50000
#define N_EDGES 800000
#define D 128
#define N_LABELS 4096
#define HB 256           // histogram blocks
#define HWORDS 12500     // 50000/4 packed u8 counters per block (50 KB LDS)
#define COUNT_BLOCKS 3125
#define FILL_BLOCKS 3125
#define PRESCALE_BLOCKS 6250   // N_NODES*32 float4 / 256
#define UVEC_BLOCKS 12500      // 4 nodes per block
#define FLAG_BLOCKS 16         // 4096 labels / 256
#define SCAN_BLOCKS 196

// ---------------------------------------------------------------------------
// K1: hetero {src out-degree LDS histogram | dst count + epos capture}
// ---------------------------------------------------------------------------

__global__ __launch_bounds__(256) void hist_count_kernel(
        const int* __restrict__ src, const int* __restrict__ dst,
        unsigned int* __restrict__ Hsrc, int* __restrict__ cnt_in,
        int* __restrict__ epos) {
    __shared__ unsigned int hist[HWORDS];
    int t = threadIdx.x;
    if (blockIdx.x < HB) {
        for (int i = t; i < HWORDS; i += 256) hist[i] = 0;
        __syncthreads();
        int base = blockIdx.x * (N_EDGES / HB);
        int end = base + (N_EDGES / HB);
        for (int e = base + t; e < end; e += 256) {
            int n = src[e];
            atomicAdd(&hist[n >> 2], 1u << ((n & 3) * 8));
        }
        __syncthreads();
        unsigned int* outp = Hsrc + (size_t)blockIdx.x * HWORDS;
        for (int i = t; i < HWORDS; i += 256) outp[i] = hist[i];
    } else {
        int e = (blockIdx.x - HB) * 256 + t;
        if (e < N_EDGES) epos[e] = atomicAdd(&cnt_in[dst[e]], 1);
    }
}

// ---------------------------------------------------------------------------
// K2: hetero {block scan of cnt_in into row_off | merge Hsrc + dinv vectors}
// ---------------------------------------------------------------------------

__global__ __launch_bounds__(256) void dinv_scan_kernel(
        const unsigned int* __restrict__ Hsrc, const int* __restrict__ cnt_in,
        float* __restrict__ dinv_out, float* __restrict__ dinv_in,
        float* __restrict__ dinv_io,
        int* __restrict__ row_off, int* __restrict__ blocksums) {
    int t = threadIdx.x;
    if (blockIdx.x < SCAN_BLOCKS) {
        __shared__ int s[256];
        int i = blockIdx.x * 256 + t;
        int v = (i < N_NODES) ? cnt_in[i] : 0;
        s[t] = v;
        __syncthreads();
        for (int offs = 1; offs < 256; offs <<= 1) {
            int add = (t >= offs) ? s[t - offs] : 0;
            __syncthreads();
            s[t] += add;
            __syncthreads();
        }
        if (i < N_NODES) row_off[i + 1] = s[t];
        if (t == 255) blocksums[blockIdx.x] = s[255];
    } else {
        int n = (blockIdx.x - SCAN_BLOCKS) * 256 + t;
        if (n >= N_NODES) return;
        int w = n >> 2, sh = (n & 3) * 8;
        unsigned int s = 0;
#pragma unroll 8
        for (int b = 0; b < HB; ++b) s += (Hsrc[(size_t)b * HWORDS + w] >> sh) & 0xFFu;
        int co = (int)s;
        int ci = cnt_in[n];
        float do_ = (co > 0) ? 1.0f / sqrtf((float)co) : 0.0f;
        float di_ = (ci > 0) ? 1.0f / sqrtf((float)ci) : 0.0f;
        dinv_out[n] = do_;
        dinv_in[n] = di_;
        dinv_io[n] = do_ * di_;
    }
}

__global__ void scan_top_kernel(const int* __restrict__ blocksums, int* __restrict__ blockoffs,
                                int nblocks) {
    __shared__ int s[256];
    int t = threadIdx.x;
    int v = (t < nblocks) ? blocksums[t] : 0;
    s[t] = v;
    __syncthreads();
    for (int offs = 1; offs < 256; offs <<= 1) {
        int add = (t >= offs) ? s[t - offs] : 0;
        __syncthreads();
        s[t] += add;
        __syncthreads();
    }
    blockoffs[t] = s[t] - v;  // exclusive
}

__global__ void scan_add_kernel(int* __restrict__ outv, const int* __restrict__ blockoffs) {
    int i = blockIdx.x * 256 + threadIdx.x;
    if (i < N_NODES) outv[i + 1] += blockoffs[blockIdx.x];
    if (i == 0) outv[0] = 0;
}

// ---------------------------------------------------------------------------
// K5: hetero {fill CSR scatter | prescale p0 = dinv_out * feat (row-major)}
// ---------------------------------------------------------------------------

__global__ __launch_bounds__(256) void fill_prescale_kernel(
        const int* __restrict__ src, const int* __restrict__ dst,
        const int* __restrict__ row_off, const int* __restrict__ epos,
        int* __restrict__ csr_src,
        const float4* __restrict__ feat4, const float* __restrict__ dinv_out,
        float4* __restrict__ p04) {
    int t = threadIdx.x;
    if (blockIdx.x < FILL_BLOCKS) {
        int e = blockIdx.x * 256 + t;
        if (e < N_EDGES) {
            int d = dst[e];
            csr_src[row_off[d] + epos[e]] = src[e];
        }
    } else {
        int i = (blockIdx.x - FILL_BLOCKS) * 256 + t;  // float4 index
        if (i < N_NODES * 32) {
            int n = i >> 5;
            float s = dinv_out[n];
            float4 v = feat4[i];
            float4 r;
            r.x = v.x * s; r.y = v.y * s; r.z = v.z * s; r.w = v.w * s;
            p04[i] = r;
        }
    }
}

// ---------------------------------------------------------------------------
// uvec body: o1[n] = s1[n]*sum g[s]; o2[n] = s2[n]*sum (optional)
// ---------------------------------------------------------------------------

__device__ __forceinline__ void uvec_body(int nb, int t,
        const int* __restrict__ csr_src, const int* __restrict__ row_off,
        const float* __restrict__ gvec, const float* __restrict__ s1,
        const float* __restrict__ s2, float* __restrict__ o1, float* __restrict__ o2) {
    int wave = t >> 6;
    int lane = t & 63;
    int n = nb * 4 + wave;
    if (n >= N_NODES) return;
    int start = row_off[n], end = row_off[n + 1];
    float a = 0.f;
    for (int j = start + lane; j < end; j += 64) a += gvec[csr_src[j]];
#pragma unroll
    for (int m = 32; m; m >>= 1) a += __shfl_xor(a, m, 64);
    if (lane == 0) {
        o1[n] = s1[n] * a;
        if (o2) o2[n] = s2[n] * a;
    }
}

// ---------------------------------------------------------------------------
// Row-major pull aggregation body (R9-proven uniform-batch inner loop)
// ---------------------------------------------------------------------------

__device__ __forceinline__ void agg_row_body(const float4* __restrict__ h4,
                                             const int* __restrict__ csr_src,
                                             int start, int end, int lane, int hw, int l32,
                                             float4& accOut) {
    float4 a0 = make_float4(0.f, 0.f, 0.f, 0.f);
    float4 a1 = a0, a2 = a0, a3 = a0;
    for (int j0 = start; j0 < end; j0 += 64) {
        int jj = j0 + lane;
        int sv = (jj < end) ? csr_src[jj] : 0;
        int nj = min(64, end - j0);
        int i = 0;
        for (; i + 8 <= nj; i += 8) {
            int s0 = __shfl(sv, i + hw, 64);
            int s1 = __shfl(sv, i + 2 + hw, 64);
            int s2 = __shfl(sv, i + 4 + hw, 64);
            int s3 = __shfl(sv, i + 6 + hw, 64);
            float4 h0 = h4[(size_t)s0 * 32 + l32];
            float4 h1 = h4[(size_t)s1 * 32 + l32];
            float4 h2 = h4[(size_t)s2 * 32 + l32];
            float4 h3 = h4[(size_t)s3 * 32 + l32];
            a0.x += h0.x; a0.y += h0.y; a0.z += h0.z; a0.w += h0.w;
            a1.x += h1.x; a1.y += h1.y; a1.z += h1.z; a1.w += h1.w;
            a2.x += h2.x; a2.y += h2.y; a2.z += h2.z; a2.w += h2.w;
            a3.x += h3.x; a3.y += h3.y; a3.z += h3.z; a3.w += h3.w;
        }
        for (; i < nj; i += 2) {
            int idx = i + hw;
            int s = __shfl(sv, idx, 64);
            if (idx < nj) {
                float4 h0 = h4[(size_t)s * 32 + l32];
                a0.x += h0.x; a0.y += h0.y; a0.z += h0.z; a0.w += h0.w;
            }
        }
    }
    accOut.x = (a0.x + a1.x) + (a2.x + a3.x);
    accOut.y = (a0.y + a1.y) + (a2.y + a3.y);
    accOut.z = (a0.z + a1.z) + (a2.z + a3.z);
    accOut.w = (a0.w + a1.w) + (a2.w + a3.w);
}

// ---------------------------------------------------------------------------
// K6: hetero {agg1: p1 = Dio A p0 | uvec1: u1,u1s | flag label-edge sources}
// ---------------------------------------------------------------------------

__global__ __launch_bounds__(256) void agg1_uvec1_flag_kernel(
        const float* __restrict__ p0, const int* __restrict__ csr_src,
        const int* __restrict__ row_off, const float* __restrict__ dinv_io,
        float* __restrict__ p1,
        const float* __restrict__ dinv_out, const float* __restrict__ dinv_in,
        float* __restrict__ u1, float* __restrict__ u1s,
        const int* __restrict__ labels, int* __restrict__ flag) {
    int t = threadIdx.x;
    if (blockIdx.x < UVEC_BLOCKS) {
        int wave = t >> 6;
        int lane = t & 63;
        int hw = lane >> 5, l32 = lane & 31;
        int n = blockIdx.x * 4 + wave;
        if (n >= N_NODES) return;
        float4 acc;
        agg_row_body((const float4*)p0, csr_src, row_off[n], row_off[n + 1], lane, hw, l32, acc);
        acc.x += __shfl_xor(acc.x, 32, 64);
        acc.y += __shfl_xor(acc.y, 32, 64);
        acc.z += __shfl_xor(acc.z, 32, 64);
        acc.w += __shfl_xor(acc.w, 32, 64);
        if (hw == 0) {
            float wi = dinv_io[n];
            float4 r;
            r.x = acc.x * wi; r.y = acc.y * wi; r.z = acc.z * wi; r.w = acc.w * wi;
            ((float4*)p1)[(size_t)n * 32 + l32] = r;
        }
    } else if (blockIdx.x < 2 * UVEC_BLOCKS) {
        uvec_body(blockIdx.x - UVEC_BLOCKS, t, csr_src, row_off, dinv_out, dinv_in, dinv_io,
                  u1, u1s);
    } else {
        int i = (blockIdx.x - 2 * UVEC_BLOCKS) * 256 + t;
        if (i < N_LABELS) {
            int n = labels[i];
            int a = row_off[n], bnd = row_off[n + 1];
            for (int j = a; j < bnd; ++j) flag[csr_src[j]] = 1;
        }
    }
}

// ---------------------------------------------------------------------------
// K7: hetero {agg2: p2 = Dio A p1 on flagged rows (write-by-node) | uvec2: u2}
// ---------------------------------------------------------------------------

__global__ __launch_bounds__(256) void agg2_uvec2_kernel(
        const float* __restrict__ p1, const int* __restrict__ csr_src,
        const int* __restrict__ row_off, const float* __restrict__ dinv_io,
        const int* __restrict__ flag, float* __restrict__ p2,
        const float* __restrict__ u1s, const float* __restrict__ dinv_in,
        float* __restrict__ u2) {
    int t = threadIdx.x;
    if (blockIdx.x < UVEC_BLOCKS) {
        int wave = t >> 6;
        int lane = t & 63;
        int hw = lane >> 5, l32 = lane & 31;
        int n = blockIdx.x * 4 + wave;
        if (n >= N_NODES) return;
        if (!flag[n]) return;
        float4 acc;
        agg_row_body((const float4*)p1, csr_src, row_off[n], row_off[n + 1], lane, hw, l32, acc);
        acc.x += __shfl_xor(acc.x, 32, 64);
        acc.y += __shfl_xor(acc.y, 32, 64);
        acc.z += __shfl_xor(acc.z, 32, 64);
        acc.w += __shfl_xor(acc.w, 32, 64);
        if (hw == 0) {
            float wi = dinv_io[n];
            float4 r;
            r.x = acc.x * wi; r.y = acc.y * wi; r.z = acc.z * wi; r.w = acc.w * wi;
            ((float4*)p2)[(size_t)n * 32 + l32] = r;
        }
    } else {
        uvec_body(blockIdx.x - UVEC_BLOCKS, t, csr_src, row_off, u1s, dinv_in, nullptr,
                  u2, nullptr);
    }
}

// ---------------------------------------------------------------------------
// K8: label-row aggregation: t = Din (A p2)[labels]
// ---------------------------------------------------------------------------

__global__ __launch_bounds__(256) void aggregate_label_kernel(
        const float* __restrict__ hs, const int* __restrict__ csr_src,
        const int* __restrict__ row_off, const float* __restrict__ scale_vec,
        float* __restrict__ outbuf, const int* __restrict__ nodeidx, int nrows) {
    int wave = threadIdx.x >> 6;
    int lane = threadIdx.x & 63;
    int hw = lane >> 5, l32 = lane & 31;
    int row = blockIdx.x * 4 + wave;
    if (row >= nrows) return;
    int n = nodeidx[row];
    float4 acc;
    agg_row_body((const float4*)hs, csr_src, row_off[n], row_off[n + 1], lane, hw, l32, acc);
    acc.x += __shfl_xor(acc.x, 32, 64);
    acc.y += __shfl_xor(acc.y, 32, 64);
    acc.z += __shfl_xor(acc.z, 32, 64);
    acc.w += __shfl_xor(acc.w, 32, 64);
    if (hw == 0) {
        float wi = scale_vec[n];
        float4 r;
        r.x = acc.x * wi; r.y = acc.y * wi; r.z = acc.z * wi; r.w = acc.w * wi;
        ((float4*)outbuf)[(size_t)row * 32 + l32] = r;
    }
}

// ---------------------------------------------------------------------------
// Small matmul (4096 rows): out[r][c] = sum_k in[r][k]*W[k][c] + brow[bidx[r]]*b[c]
// ---------------------------------------------------------------------------

__global__ __launch_bounds__(256) void matmul16_kernel(
        const float* __restrict__ in, const float* __restrict__ W,
        const float* __restrict__ b, const float* __restrict__ brow,
        const int* __restrict__ bidx, float* __restrict__ outbuf, int nrows) {
    int t = threadIdx.x;
    int tx = t & 15, ty = t >> 4;
    int r = blockIdx.x * 16 + ty;
    if (r >= nrows) return;

    const float4* in4 = (const float4*)in;
    const float4* W4 = (const float4*)W;

    float bs = 1.0f;
    if (brow) bs = bidx ? brow[bidx[r]] : brow[r];
    float4 bv0 = ((const float4*)b)[tx * 2];
    float4 bv1 = ((const float4*)b)[tx * 2 + 1];

    float acc[8];
    acc[0] = bs * bv0.x; acc[1] = bs * bv0.y; acc[2] = bs * bv0.z; acc[3] = bs * bv0.w;
    acc[4] = bs * bv1.x; acc[5] = bs * bv1.y; acc[6] = bs * bv1.z; acc[7] = bs * bv1.w;

#pragma unroll 4
    for (int kb = 0; kb < 32; ++kb) {
        float4 a = in4[(size_t)r * 32 + kb];
        int k4 = kb * 4;
#define MM16_STEP(kk, comp)                                           \
        {                                                             \
            float4 w0 = W4[(size_t)(k4 + kk) * 32 + tx * 2];          \
            float4 w1 = W4[(size_t)(k4 + kk) * 32 + tx * 2 + 1];      \
            acc[0] = fmaf(a.comp, w0.x, acc[0]);                      \
            acc[1] = fmaf(a.comp, w0.y, acc[1]);                      \
            acc[2] = fmaf(a.comp, w0.z, acc[2]);                      \
            acc[3] = fmaf(a.comp, w0.w, acc[3]);                      \
            acc[4] = fmaf(a.comp, w1.x, acc[4]);                      \
            acc[5] = fmaf(a.comp, w1.y, acc[5]);                      \
            acc[6] = fmaf(a.comp, w1.z, acc[6]);                      \
            acc[7] = fmaf(a.comp, w1.w, acc[7]);                      \
        }
        MM16_STEP(0, x)
        MM16_STEP(1, y)
        MM16_STEP(2, z)
        MM16_STEP(3, w)
#undef MM16_STEP
    }

    float4 o0, o1;
    o0.x = acc[0]; o0.y = acc[1]; o0.z = acc[2]; o0.w = acc[3];
    o1.x = acc[4]; o1.y = acc[5]; o1.z = acc[6]; o1.w = acc[7];
    float4* op = (float4*)&outbuf[(size_t)r * D + tx * 8];
    op[0] = o0;
    op[1] = o1;
}

// ---------------------------------------------------------------------------

extern "C" void kernel_launch(void* const* d_in, const int* in_sizes, int n_in,
                              void* d_out, int out_size, void* d_ws, size_t ws_size,
                              hipStream_t stream) {
    const int* labels = (const int*)d_in[0];
    const int* src    = (const int*)d_in[1];
    const int* dst    = (const int*)d_in[2];
    const float* feat = (const float*)d_in[3];
    const float* W0   = (const float*)d_in[4];
    const float* b0   = (const float*)d_in[5];
    const float* W1   = (const float*)d_in[6];
    const float* b1   = (const float*)d_in[7];
    const float* W2   = (const float*)d_in[8];
    const float* b2   = (const float*)d_in[9];
    float* out = (float*)d_out;

    char* ws = (char*)d_ws;
    size_t off = 0;
    auto alloc = [&](size_t bytes) -> void* {
        void* p = ws + off;
        off = (off + bytes + 255) & ~(size_t)255;
        return p;
    };
    int* row_off    = (int*)alloc((N_NODES + 1) * 4);
    int* blocksums  = (int*)alloc(256 * 4);
    int* blockoffs  = (int*)alloc(256 * 4);
    int* csr_src    = (int*)alloc((size_t)N_EDGES * 4);
    int* epos       = (int*)alloc((size_t)N_EDGES * 4);
    int* cnt_in     = (int*)alloc(N_NODES * 4);
    int* flag       = (int*)alloc(N_NODES * 4);
    float* dinv_out = (float*)alloc(N_NODES * 4);
    float* dinv_in  = (float*)alloc(N_NODES * 4);
    float* dinv_io  = (float*)alloc(N_NODES * 4);
    float* u1       = (float*)alloc(N_NODES * 4);
    float* u1s      = (float*)alloc(N_NODES * 4);
    float* u2       = (float*)alloc(N_NODES * 4);
    float* BUF1 = (float*)alloc((size_t)N_NODES * D * 4);  // p0 | p2
    float* BUF2 = (float*)alloc((size_t)N_NODES * D * 4);  // Hsrc | p1 | tbuf/z1/z2

    // aliases (stream-ordered lifetimes):
    unsigned int* Hsrc = (unsigned int*)BUF2;        // dead after dinv; p1 written later
    float* p0 = BUF1;                                // written by K5, read by K6
    float* p1 = BUF2;                                // written by K6, read by K7
    float* p2 = BUF1;                                // p0 dead after K6
    float* tbuf = BUF2;                              // p1 dead after K7
    float* z1 = BUF2 + (size_t)N_LABELS * D;
    float* z2 = BUF2 + (size_t)2 * N_LABELS * D;

    hipMemsetAsync(cnt_in, 0, N_NODES * 4, stream);
    hipMemsetAsync(flag, 0, N_NODES * 4, stream);

    // K1: hist + count
    hist_count_kernel<<<HB + COUNT_BLOCKS, 256, 0, stream>>>(src, dst, Hsrc, cnt_in, epos);
    // K2: scan(cnt_in) + dinv (hetero)
    dinv_scan_kernel<<<SCAN_BLOCKS + SCAN_BLOCKS, 256, 0, stream>>>(
        Hsrc, cnt_in, dinv_out, dinv_in, dinv_io, row_off, blocksums);
    // K3-4: finish row_off scan
    scan_top_kernel<<<1, 256, 0, stream>>>(blocksums, blockoffs, SCAN_BLOCKS);
    scan_add_kernel<<<SCAN_BLOCKS, 256, 0, stream>>>(row_off, blockoffs);
    // K5: fill + prescale
    fill_prescale_kernel<<<FILL_BLOCKS + PRESCALE_BLOCKS, 256, 0, stream>>>(
        src, dst, row_off, epos, csr_src, (const float4*)feat, dinv_out, (float4*)p0);
    // K6: agg1 + uvec1 + flag
    agg1_uvec1_flag_kernel<<<2 * UVEC_BLOCKS + FLAG_BLOCKS, 256, 0, stream>>>(
        p0, csr_src, row_off, dinv_io, p1, dinv_out, dinv_in, u1, u1s, labels, flag);
    // K7: agg2 (flag-guarded) + uvec2
    agg2_uvec2_kernel<<<2 * UVEC_BLOCKS, 256, 0, stream>>>(
        p1, csr_src, row_off, dinv_io, flag, p2, u1s, dinv_in, u2);
    // K8: t = Din (A p2)[labels]
    aggregate_label_kernel<<<(N_LABELS + 3) / 4, 256, 0, stream>>>(
        p2, csr_src, row_off, dinv_in, tbuf, labels, N_LABELS);

    // K9-11: z1 = t@W0 + u2[labels]*b0 ; z2 = z1@W1 + u1[labels]*b1 ; out = z2@W2 + b2
    const int mmGrid = (N_LABELS + 15) / 16;  // 256 blocks
    matmul16_kernel<<<mmGrid, 256, 0, stream>>>(tbuf, W0, b0, u2, labels, z1, N_LABELS);
    matmul16_kernel<<<mmGrid, 256, 0, stream>>>(z1, W1, b1, u1, labels, z2, N_LABELS);
    matmul16_kernel<<<mmGrid, 256, 0, stream>>>(z2, W2, b2, nullptr, nullptr, out, N_LABELS);
}

// Round 11
// 234.231 us; speedup vs baseline: 2.0659x; 1.0984x over previous
//
#include <hip/hip_runtime.h>

#define N_NODES 50000
#define N_EDGES 800000
#define D 128
#define N_LABELS 4096
#define HB 256           // histogram blocks
#define HWORDS 12500     // 50000/4 packed u8 counters per block (50 KB LDS)
#define COUNT_BLOCKS 3125
#define FILL_BLOCKS 3125
#define PRESCALE_BLOCKS 6250   // N_NODES*32 float4 / 256
#define UVEC_BLOCKS 12500      // 4 nodes per block
#define FLAG_BLOCKS 16         // 4096 labels / 256
#define SCAN_BLOCKS 196
#define MMW_BLOCKS 8           // 128x128 matmul, 16 rows/block

// ---------------------------------------------------------------------------
// small dense helpers (fp32, no LDS, W L1/L2-resident)
// ---------------------------------------------------------------------------

#define MM16_STEP(kk, comp)                                           \
    {                                                                 \
        float4 w0 = W4[(size_t)(k4 + kk) * 32 + tx * 2];              \
        float4 w1 = W4[(size_t)(k4 + kk) * 32 + tx * 2 + 1];          \
        acc[0] = fmaf(a.comp, w0.x, acc[0]);                          \
        acc[1] = fmaf(a.comp, w0.y, acc[1]);                          \
        acc[2] = fmaf(a.comp, w0.z, acc[2]);                          \
        acc[3] = fmaf(a.comp, w0.w, acc[3]);                          \
        acc[4] = fmaf(a.comp, w1.x, acc[4]);                          \
        acc[5] = fmaf(a.comp, w1.y, acc[5]);                          \
        acc[6] = fmaf(a.comp, w1.z, acc[6]);                          \
        acc[7] = fmaf(a.comp, w1.w, acc[7]);                          \
    }

// C[r0..r0+16) = A[r0..r0+16) @ W   (A, C are [*,128]; W is [128,128])
__device__ __forceinline__ void mm_tile16(const float* __restrict__ A,
                                          const float* __restrict__ W,
                                          float* __restrict__ C, int r0, int t) {
    int tx = t & 15, ty = t >> 4;
    int r = r0 + ty;
    const float4* A4 = (const float4*)A;
    const float4* W4 = (const float4*)W;
    float acc[8] = {0.f, 0.f, 0.f, 0.f, 0.f, 0.f, 0.f, 0.f};
#pragma unroll 4
    for (int kb = 0; kb < 32; ++kb) {
        float4 a = A4[(size_t)r * 32 + kb];
        int k4 = kb * 4;
        MM16_STEP(0, x)
        MM16_STEP(1, y)
        MM16_STEP(2, z)
        MM16_STEP(3, w)
    }
    float4* cp = (float4*)&C[(size_t)r * D + tx * 8];
    float4 o0, o1;
    o0.x = acc[0]; o0.y = acc[1]; o0.z = acc[2]; o0.w = acc[3];
    o1.x = acc[4]; o1.y = acc[5]; o1.z = acc[6]; o1.w = acc[7];
    cp[0] = o0;
    cp[1] = o1;
}

// outp = v @ W  (v:[128], W:[128,128])
__device__ __forceinline__ void vecmat128(const float* __restrict__ v,
                                          const float* __restrict__ W,
                                          float* __restrict__ outp, int t) {
    if (t < D) {
        float acc = 0.f;
#pragma unroll 8
        for (int k = 0; k < D; ++k) acc = fmaf(v[k], W[(size_t)k * D + t], acc);
        outp[t] = acc;
    }
}

// ---------------------------------------------------------------------------
// K1: hetero {src LDS histogram | dst count + epos | W01 = W0@W1 | bv01 = b0@W1}
// ---------------------------------------------------------------------------

__global__ __launch_bounds__(256) void hist_count_w_kernel(
        const int* __restrict__ src, const int* __restrict__ dst,
        unsigned int* __restrict__ Hsrc, int* __restrict__ cnt_in,
        int* __restrict__ epos,
        const float* __restrict__ W0, const float* __restrict__ W1,
        const float* __restrict__ b0, float* __restrict__ W01,
        float* __restrict__ bv01) {
    __shared__ unsigned int hist[HWORDS];
    int t = threadIdx.x;
    if (blockIdx.x < HB) {
        for (int i = t; i < HWORDS; i += 256) hist[i] = 0;
        __syncthreads();
        int base = blockIdx.x * (N_EDGES / HB);
        int end = base + (N_EDGES / HB);
        for (int e = base + t; e < end; e += 256) {
            int n = src[e];
            atomicAdd(&hist[n >> 2], 1u << ((n & 3) * 8));
        }
        __syncthreads();
        unsigned int* outp = Hsrc + (size_t)blockIdx.x * HWORDS;
        for (int i = t; i < HWORDS; i += 256) outp[i] = hist[i];
    } else if (blockIdx.x < HB + COUNT_BLOCKS) {
        int e = (blockIdx.x - HB) * 256 + t;
        if (e < N_EDGES) epos[e] = atomicAdd(&cnt_in[dst[e]], 1);
    } else if (blockIdx.x < HB + COUNT_BLOCKS + MMW_BLOCKS) {
        mm_tile16(W0, W1, W01, (blockIdx.x - HB - COUNT_BLOCKS) * 16, t);
    } else {
        vecmat128(b0, W1, bv01, t);
    }
}

// ---------------------------------------------------------------------------
// K2: hetero {scan cnt_in | dinv merge | Wc = W01@W2 | bc1 = bv01@W2 | bc2 = b1@W2}
// ---------------------------------------------------------------------------

__global__ __launch_bounds__(256) void dinv_scan_w_kernel(
        const unsigned int* __restrict__ Hsrc, const int* __restrict__ cnt_in,
        float* __restrict__ dinv_out, float* __restrict__ dinv_in,
        float* __restrict__ dinv_io,
        int* __restrict__ row_off, int* __restrict__ blocksums,
        const float* __restrict__ W01, const float* __restrict__ W2,
        const float* __restrict__ bv01, const float* __restrict__ b1,
        float* __restrict__ Wc, float* __restrict__ bc1, float* __restrict__ bc2) {
    int t = threadIdx.x;
    if (blockIdx.x < SCAN_BLOCKS) {
        __shared__ int s[256];
        int i = blockIdx.x * 256 + t;
        int v = (i < N_NODES) ? cnt_in[i] : 0;
        s[t] = v;
        __syncthreads();
        for (int offs = 1; offs < 256; offs <<= 1) {
            int add = (t >= offs) ? s[t - offs] : 0;
            __syncthreads();
            s[t] += add;
            __syncthreads();
        }
        if (i < N_NODES) row_off[i + 1] = s[t];
        if (t == 255) blocksums[blockIdx.x] = s[255];
    } else if (blockIdx.x < 2 * SCAN_BLOCKS) {
        int n = (blockIdx.x - SCAN_BLOCKS) * 256 + t;
        if (n >= N_NODES) return;
        int w = n >> 2, sh = (n & 3) * 8;
        unsigned int s = 0;
#pragma unroll 8
        for (int b = 0; b < HB; ++b) s += (Hsrc[(size_t)b * HWORDS + w] >> sh) & 0xFFu;
        int co = (int)s;
        int ci = cnt_in[n];
        float do_ = (co > 0) ? 1.0f / sqrtf((float)co) : 0.0f;
        float di_ = (ci > 0) ? 1.0f / sqrtf((float)ci) : 0.0f;
        dinv_out[n] = do_;
        dinv_in[n] = di_;
        dinv_io[n] = do_ * di_;
    } else if (blockIdx.x < 2 * SCAN_BLOCKS + MMW_BLOCKS) {
        mm_tile16(W01, W2, Wc, (blockIdx.x - 2 * SCAN_BLOCKS) * 16, t);
    } else if (blockIdx.x == 2 * SCAN_BLOCKS + MMW_BLOCKS) {
        vecmat128(bv01, W2, bc1, t);
    } else {
        vecmat128(b1, W2, bc2, t);
    }
}

__global__ void scan_top_kernel(const int* __restrict__ blocksums, int* __restrict__ blockoffs,
                                int nblocks) {
    __shared__ int s[256];
    int t = threadIdx.x;
    int v = (t < nblocks) ? blocksums[t] : 0;
    s[t] = v;
    __syncthreads();
    for (int offs = 1; offs < 256; offs <<= 1) {
        int add = (t >= offs) ? s[t - offs] : 0;
        __syncthreads();
        s[t] += add;
        __syncthreads();
    }
    blockoffs[t] = s[t] - v;  // exclusive
}

__global__ void scan_add_kernel(int* __restrict__ outv, const int* __restrict__ blockoffs) {
    int i = blockIdx.x * 256 + threadIdx.x;
    if (i < N_NODES) outv[i + 1] += blockoffs[blockIdx.x];
    if (i == 0) outv[0] = 0;
}

// ---------------------------------------------------------------------------
// K5: hetero {fill CSR scatter | prescale p0 = dinv_out * feat (row-major)}
// ---------------------------------------------------------------------------

__global__ __launch_bounds__(256) void fill_prescale_kernel(
        const int* __restrict__ src, const int* __restrict__ dst,
        const int* __restrict__ row_off, const int* __restrict__ epos,
        int* __restrict__ csr_src,
        const float4* __restrict__ feat4, const float* __restrict__ dinv_out,
        float4* __restrict__ p04) {
    int t = threadIdx.x;
    if (blockIdx.x < FILL_BLOCKS) {
        int e = blockIdx.x * 256 + t;
        if (e < N_EDGES) {
            int d = dst[e];
            csr_src[row_off[d] + epos[e]] = src[e];
        }
    } else {
        int i = (blockIdx.x - FILL_BLOCKS) * 256 + t;  // float4 index
        if (i < N_NODES * 32) {
            int n = i >> 5;
            float s = dinv_out[n];
            float4 v = feat4[i];
            float4 r;
            r.x = v.x * s; r.y = v.y * s; r.z = v.z * s; r.w = v.w * s;
            p04[i] = r;
        }
    }
}

// ---------------------------------------------------------------------------
// uvec body: o1[n] = s1[n]*sum g[s]; o2[n] = s2[n]*sum (optional)
// ---------------------------------------------------------------------------

__device__ __forceinline__ void uvec_body(int nb, int t,
        const int* __restrict__ csr_src, const int* __restrict__ row_off,
        const float* __restrict__ gvec, const float* __restrict__ s1,
        const float* __restrict__ s2, float* __restrict__ o1, float* __restrict__ o2) {
    int wave = t >> 6;
    int lane = t & 63;
    int n = nb * 4 + wave;
    if (n >= N_NODES) return;
    int start = row_off[n], end = row_off[n + 1];
    float a = 0.f;
    for (int j = start + lane; j < end; j += 64) a += gvec[csr_src[j]];
#pragma unroll
    for (int m = 32; m; m >>= 1) a += __shfl_xor(a, m, 64);
    if (lane == 0) {
        o1[n] = s1[n] * a;
        if (o2) o2[n] = s2[n] * a;
    }
}

// ---------------------------------------------------------------------------
// Row-major pull aggregation body (uniform-batch inner loop, R9-proven)
// ---------------------------------------------------------------------------

__device__ __forceinline__ void agg_row_body(const float4* __restrict__ h4,
                                             const int* __restrict__ csr_src,
                                             int start, int end, int lane, int hw, int l32,
                                             float4& accOut) {
    float4 a0 = make_float4(0.f, 0.f, 0.f, 0.f);
    float4 a1 = a0, a2 = a0, a3 = a0;
    for (int j0 = start; j0 < end; j0 += 64) {
        int jj = j0 + lane;
        int sv = (jj < end) ? csr_src[jj] : 0;
        int nj = min(64, end - j0);
        int i = 0;
        for (; i + 8 <= nj; i += 8) {
            int s0 = __shfl(sv, i + hw, 64);
            int s1 = __shfl(sv, i + 2 + hw, 64);
            int s2 = __shfl(sv, i + 4 + hw, 64);
            int s3 = __shfl(sv, i + 6 + hw, 64);
            float4 h0 = h4[(size_t)s0 * 32 + l32];
            float4 h1 = h4[(size_t)s1 * 32 + l32];
            float4 h2 = h4[(size_t)s2 * 32 + l32];
            float4 h3 = h4[(size_t)s3 * 32 + l32];
            a0.x += h0.x; a0.y += h0.y; a0.z += h0.z; a0.w += h0.w;
            a1.x += h1.x; a1.y += h1.y; a1.z += h1.z; a1.w += h1.w;
            a2.x += h2.x; a2.y += h2.y; a2.z += h2.z; a2.w += h2.w;
            a3.x += h3.x; a3.y += h3.y; a3.z += h3.z; a3.w += h3.w;
        }
        for (; i < nj; i += 2) {
            int idx = i + hw;
            int s = __shfl(sv, idx, 64);
            if (idx < nj) {
                float4 h0 = h4[(size_t)s * 32 + l32];
                a0.x += h0.x; a0.y += h0.y; a0.z += h0.z; a0.w += h0.w;
            }
        }
    }
    accOut.x = (a0.x + a1.x) + (a2.x + a3.x);
    accOut.y = (a0.y + a1.y) + (a2.y + a3.y);
    accOut.z = (a0.z + a1.z) + (a2.z + a3.z);
    accOut.w = (a0.w + a1.w) + (a2.w + a3.w);
}

// ---------------------------------------------------------------------------
// K6: hetero {agg1: p1 = Dio A p0 | uvec1: u1,u1s | flag label-edge sources}
// ---------------------------------------------------------------------------

__global__ __launch_bounds__(256) void agg1_uvec1_flag_kernel(
        const float* __restrict__ p0, const int* __restrict__ csr_src,
        const int* __restrict__ row_off, const float* __restrict__ dinv_io,
        float* __restrict__ p1,
        const float* __restrict__ dinv_out, const float* __restrict__ dinv_in,
        float* __restrict__ u1, float* __restrict__ u1s,
        const int* __restrict__ labels, int* __restrict__ flag) {
    int t = threadIdx.x;
    if (blockIdx.x < UVEC_BLOCKS) {
        int wave = t >> 6;
        int lane = t & 63;
        int hw = lane >> 5, l32 = lane & 31;
        int n = blockIdx.x * 4 + wave;
        if (n >= N_NODES) return;
        float4 acc;
        agg_row_body((const float4*)p0, csr_src, row_off[n], row_off[n + 1], lane, hw, l32, acc);
        acc.x += __shfl_xor(acc.x, 32, 64);
        acc.y += __shfl_xor(acc.y, 32, 64);
        acc.z += __shfl_xor(acc.z, 32, 64);
        acc.w += __shfl_xor(acc.w, 32, 64);
        if (hw == 0) {
            float wi = dinv_io[n];
            float4 r;
            r.x = acc.x * wi; r.y = acc.y * wi; r.z = acc.z * wi; r.w = acc.w * wi;
            ((float4*)p1)[(size_t)n * 32 + l32] = r;
        }
    } else if (blockIdx.x < 2 * UVEC_BLOCKS) {
        uvec_body(blockIdx.x - UVEC_BLOCKS, t, csr_src, row_off, dinv_out, dinv_in, dinv_io,
                  u1, u1s);
    } else {
        int i = (blockIdx.x - 2 * UVEC_BLOCKS) * 256 + t;
        if (i < N_LABELS) {
            int n = labels[i];
            int a = row_off[n], bnd = row_off[n + 1];
            for (int j = a; j < bnd; ++j) flag[csr_src[j]] = 1;
        }
    }
}

// ---------------------------------------------------------------------------
// K7: hetero {agg2: p2 = Dio A p1 on flagged rows (write-by-node) | uvec2: u2}
// ---------------------------------------------------------------------------

__global__ __launch_bounds__(256) void agg2_uvec2_kernel(
        const float* __restrict__ p1, const int* __restrict__ csr_src,
        const int* __restrict__ row_off, const float* __restrict__ dinv_io,
        const int* __restrict__ flag, float* __restrict__ p2,
        const float* __restrict__ u1s, const float* __restrict__ dinv_in,
        float* __restrict__ u2) {
    int t = threadIdx.x;
    if (blockIdx.x < UVEC_BLOCKS) {
        int wave = t >> 6;
        int lane = t & 63;
        int hw = lane >> 5, l32 = lane & 31;
        int n = blockIdx.x * 4 + wave;
        if (n >= N_NODES) return;
        if (!flag[n]) return;
        float4 acc;
        agg_row_body((const float4*)p1, csr_src, row_off[n], row_off[n + 1], lane, hw, l32, acc);
        acc.x += __shfl_xor(acc.x, 32, 64);
        acc.y += __shfl_xor(acc.y, 32, 64);
        acc.z += __shfl_xor(acc.z, 32, 64);
        acc.w += __shfl_xor(acc.w, 32, 64);
        if (hw == 0) {
            float wi = dinv_io[n];
            float4 r;
            r.x = acc.x * wi; r.y = acc.y * wi; r.z = acc.z * wi; r.w = acc.w * wi;
            ((float4*)p2)[(size_t)n * 32 + l32] = r;
        }
    } else {
        uvec_body(blockIdx.x - UVEC_BLOCKS, t, csr_src, row_off, u1s, dinv_in, nullptr,
                  u2, nullptr);
    }
}

// ---------------------------------------------------------------------------
// K8: fused {label-row aggregation -> LDS | 16-row matmul vs Wc + rank-1 biases}
//   t_r = dinv_in[n] * (A p2)[n],  n = labels[r]
//   out[r] = t_r @ Wc + u2[n]*bc1 + u1[n]*bc2 + b2
// ---------------------------------------------------------------------------

__global__ __launch_bounds__(256) void agg_label_matmul_kernel(
        const float* __restrict__ p2, const int* __restrict__ csr_src,
        const int* __restrict__ row_off, const float* __restrict__ dinv_in,
        const int* __restrict__ labels,
        const float* __restrict__ Wc, const float* __restrict__ bc1,
        const float* __restrict__ bc2, const float* __restrict__ b2,
        const float* __restrict__ u1, const float* __restrict__ u2,
        float* __restrict__ outbuf) {
    __shared__ float tl[16][D];
    int t = threadIdx.x;
    int wave = t >> 6, lane = t & 63;
    int hw = lane >> 5, l32 = lane & 31;
    int rbase = blockIdx.x * 16;
#pragma unroll
    for (int rr = 0; rr < 4; ++rr) {
        int row = rbase + wave * 4 + rr;
        int n = labels[row];
        float4 acc;
        agg_row_body((const float4*)p2, csr_src, row_off[n], row_off[n + 1], lane, hw, l32, acc);
        acc.x += __shfl_xor(acc.x, 32, 64);
        acc.y += __shfl_xor(acc.y, 32, 64);
        acc.z += __shfl_xor(acc.z, 32, 64);
        acc.w += __shfl_xor(acc.w, 32, 64);
        if (hw == 0) {
            float wi = dinv_in[n];
            float4 r;
            r.x = acc.x * wi; r.y = acc.y * wi; r.z = acc.z * wi; r.w = acc.w * wi;
            ((float4*)&tl[wave * 4 + rr][0])[l32] = r;
        }
    }
    __syncthreads();

    int tx = t & 15, ty = t >> 4;
    int r = rbase + ty;
    int lab = labels[r];
    float s2 = u2[lab], s1 = u1[lab];
    float4 c10 = ((const float4*)bc1)[tx * 2];
    float4 c11 = ((const float4*)bc1)[tx * 2 + 1];
    float4 c20 = ((const float4*)bc2)[tx * 2];
    float4 c21 = ((const float4*)bc2)[tx * 2 + 1];
    float4 bz0 = ((const float4*)b2)[tx * 2];
    float4 bz1 = ((const float4*)b2)[tx * 2 + 1];

    float acc[8];
    acc[0] = fmaf(s2, c10.x, fmaf(s1, c20.x, bz0.x));
    acc[1] = fmaf(s2, c10.y, fmaf(s1, c20.y, bz0.y));
    acc[2] = fmaf(s2, c10.z, fmaf(s1, c20.z, bz0.z));
    acc[3] = fmaf(s2, c10.w, fmaf(s1, c20.w, bz0.w));
    acc[4] = fmaf(s2, c11.x, fmaf(s1, c21.x, bz1.x));
    acc[5] = fmaf(s2, c11.y, fmaf(s1, c21.y, bz1.y));
    acc[6] = fmaf(s2, c11.z, fmaf(s1, c21.z, bz1.z));
    acc[7] = fmaf(s2, c11.w, fmaf(s1, c21.w, bz1.w));

    const float4* W4 = (const float4*)Wc;
#pragma unroll 4
    for (int kb = 0; kb < 32; ++kb) {
        float4 a = ((const float4*)&tl[ty][0])[kb];
        int k4 = kb * 4;
        MM16_STEP(0, x)
        MM16_STEP(1, y)
        MM16_STEP(2, z)
        MM16_STEP(3, w)
    }

    float4 o0, o1;
    o0.x = acc[0]; o0.y = acc[1]; o0.z = acc[2]; o0.w = acc[3];
    o1.x = acc[4]; o1.y = acc[5]; o1.z = acc[6]; o1.w = acc[7];
    float4* op = (float4*)&outbuf[(size_t)r * D + tx * 8];
    op[0] = o0;
    op[1] = o1;
}

// ---------------------------------------------------------------------------

extern "C" void kernel_launch(void* const* d_in, const int* in_sizes, int n_in,
                              void* d_out, int out_size, void* d_ws, size_t ws_size,
                              hipStream_t stream) {
    const int* labels = (const int*)d_in[0];
    const int* src    = (const int*)d_in[1];
    const int* dst    = (const int*)d_in[2];
    const float* feat = (const float*)d_in[3];
    const float* W0   = (const float*)d_in[4];
    const float* b0   = (const float*)d_in[5];
    const float* W1   = (const float*)d_in[6];
    const float* b1   = (const float*)d_in[7];
    const float* W2   = (const float*)d_in[8];
    const float* b2   = (const float*)d_in[9];
    float* out = (float*)d_out;

    char* ws = (char*)d_ws;
    size_t off = 0;
    auto alloc = [&](size_t bytes) -> void* {
        void* p = ws + off;
        off = (off + bytes + 255) & ~(size_t)255;
        return p;
    };
    int* row_off    = (int*)alloc((N_NODES + 1) * 4);
    int* blocksums  = (int*)alloc(256 * 4);
    int* blockoffs  = (int*)alloc(256 * 4);
    int* csr_src    = (int*)alloc((size_t)N_EDGES * 4);
    int* epos       = (int*)alloc((size_t)N_EDGES * 4);
    int* cnt_in     = (int*)alloc(N_NODES * 4);
    int* flag       = (int*)alloc(N_NODES * 4);   // adjacent to cnt_in: one memset covers both
    float* dinv_out = (float*)alloc(N_NODES * 4);
    float* dinv_in  = (float*)alloc(N_NODES * 4);
    float* dinv_io  = (float*)alloc(N_NODES * 4);
    float* u1       = (float*)alloc(N_NODES * 4);
    float* u1s      = (float*)alloc(N_NODES * 4);
    float* u2       = (float*)alloc(N_NODES * 4);
    float* W01      = (float*)alloc((size_t)D * D * 4);
    float* Wc       = (float*)alloc((size_t)D * D * 4);
    float* bv01     = (float*)alloc(D * 4);
    float* bc1      = (float*)alloc(D * 4);
    float* bc2      = (float*)alloc(D * 4);
    float* BUF1 = (float*)alloc((size_t)N_NODES * D * 4);  // p0 | p2
    float* BUF2 = (float*)alloc((size_t)N_NODES * D * 4);  // Hsrc | p1

    // aliases (stream-ordered lifetimes):
    unsigned int* Hsrc = (unsigned int*)BUF2;        // dead after K2; p1 written later
    float* p0 = BUF1;                                // written by K5, read by K6
    float* p1 = BUF2;                                // written by K6, read by K7
    float* p2 = BUF1;                                // p0 dead after K6

    // one memset covers cnt_in + pad + flag (pad bytes harmless)
    size_t zlen = (size_t)((char*)flag - (char*)cnt_in) + (size_t)N_NODES * 4;
    hipMemsetAsync(cnt_in, 0, zlen, stream);

    // K1: hist + count + W01 + bv01
    hist_count_w_kernel<<<HB + COUNT_BLOCKS + MMW_BLOCKS + 1, 256, 0, stream>>>(
        src, dst, Hsrc, cnt_in, epos, W0, W1, b0, W01, bv01);
    // K2: scan(cnt_in) + dinv + Wc + bc1 + bc2
    dinv_scan_w_kernel<<<2 * SCAN_BLOCKS + MMW_BLOCKS + 2, 256, 0, stream>>>(
        Hsrc, cnt_in, dinv_out, dinv_in, dinv_io, row_off, blocksums,
        W01, W2, bv01, b1, Wc, bc1, bc2);
    // K3-4: finish row_off scan
    scan_top_kernel<<<1, 256, 0, stream>>>(blocksums, blockoffs, SCAN_BLOCKS);
    scan_add_kernel<<<SCAN_BLOCKS, 256, 0, stream>>>(row_off, blockoffs);
    // K5: fill + prescale
    fill_prescale_kernel<<<FILL_BLOCKS + PRESCALE_BLOCKS, 256, 0, stream>>>(
        src, dst, row_off, epos, csr_src, (const float4*)feat, dinv_out, (float4*)p0);
    // K6: agg1 + uvec1 + flag
    agg1_uvec1_flag_kernel<<<2 * UVEC_BLOCKS + FLAG_BLOCKS, 256, 0, stream>>>(
        p0, csr_src, row_off, dinv_io, p1, dinv_out, dinv_in, u1, u1s, labels, flag);
    // K7: agg2 (flag-guarded) + uvec2
    agg2_uvec2_kernel<<<2 * UVEC_BLOCKS, 256, 0, stream>>>(
        p1, csr_src, row_off, dinv_io, flag, p2, u1s, dinv_in, u2);
    // K8: fused label agg + final matmul
    agg_label_matmul_kernel<<<N_LABELS / 16, 256, 0, stream>>>(
        p2, csr_src, row_off, dinv_in, labels, Wc, bc1, bc2, b2, u1, u2, out);
}